// Round 1
// baseline (58928.583 us; speedup 1.0000x reference)
//
#include <hip/hip_runtime.h>
#include <hip/hip_bf16.h>
#include <hip/hip_cooperative_groups.h>

namespace cg = cooperative_groups;

// Problem constants
#define B_    32
#define TO_   256
#define T_    257        // To+1 decode steps
#define H_    512
#define V_    10000
#define TI_   1024
#define NROW_ 8224       // T_*B_

using f32x4 = __attribute__((ext_vector_type(4))) float;
using s16x8 = __attribute__((ext_vector_type(8))) short;

struct Ptrs {
  const int* padded;
  const float* enc;
  const float* emb;
  const float *Wih0, *Whh0, *bih0, *bhh0;
  const float *Wih1, *Whh1, *bih1, *bhh1;
  const float *W1, *b1, *W2, *b2;
  float* out;
  // workspace
  unsigned short *mlpin;   // [257][32][1024] bf16  (=[h1 | att_c])
  unsigned short *tanhv;   // [8224][512] bf16
  unsigned short *W1b;     // [512][1024] bf16
  unsigned short *W2b;     // [10000][512] bf16
  float *h0, *h1;          // [2][32][512] double-buffered
  float *c0, *c1;          // [32][512]
  float *u;                // [2][32][512] unnormalized context
  float *Zb;               // [2][32] softmax denominators
  unsigned *smax;          // [2][32] int-encoded score max
  float *rowsum;           // [8224] sum exp(logits)
  float *lablog;           // [8224] logit at label
};

__device__ __forceinline__ unsigned short f2b(float f){
  __hip_bfloat16 h = __float2bfloat16(f);
  unsigned short r; __builtin_memcpy(&r, &h, 2); return r;
}
__device__ __forceinline__ float b2f(unsigned short u){
  unsigned v = ((unsigned)u) << 16; float f; __builtin_memcpy(&f, &v, 4); return f;
}
// order-preserving float<->uint encoding for atomicMax
__device__ __forceinline__ unsigned fenc(float f){
  unsigned u = __float_as_uint(f);
  return (u & 0x80000000u) ? ~u : (u | 0x80000000u);
}
__device__ __forceinline__ float fdec(unsigned e){
  unsigned u = (e & 0x80000000u) ? (e ^ 0x80000000u) : ~e;
  return __uint_as_float(u);
}
__device__ __forceinline__ float sigf(float x){ return 1.f / (1.f + expf(-x)); }

// ------------------------------------------------------------------
// prep: bf16-convert W1/W2, zero rowsum
__global__ __launch_bounds__(256) void kprep(Ptrs P){
  const int stride = gridDim.x * blockDim.x;
  const int i0 = blockIdx.x * blockDim.x + threadIdx.x;
  for (int i = i0; i < 512 * 1024; i += stride) P.W1b[i] = f2b(P.W1[i]);
  for (int i = i0; i < V_ * 512;   i += stride) P.W2b[i] = f2b(P.W2[i]);
  for (int i = i0; i < NROW_;      i += stride) P.rowsum[i] = 0.f;
}

// ------------------------------------------------------------------
// Phase A: persistent cooperative recurrence.
// block bb: attention slice (b_att = bb>>3, ti chunk = (bb&7)*128..+128) kept in LDS (bf16, swizzled);
// LSTM work: block owns hidden indices j in {2bb, 2bb+1} across all 4 gates, all 32 batches.
__global__ __launch_bounds__(256, 1) void kA(Ptrs P){
  __shared__ __align__(16) unsigned short enc_s[128 * 512]; // 128 KB, XOR-swizzled
  __shared__ float h1_s[512];
  __shared__ float w_s[128];
  __shared__ float gate_s[32][8];
  cg::grid_group grid = cg::this_grid();
  const int bb = blockIdx.x, tid = threadIdx.x;
  const int b_att = bb >> 3, tc = bb & 7;

  { // stage encoder slice -> LDS bf16 with byte^=((row&7)<<4) swizzle
    const float* ep = P.enc + ((size_t)b_att * TI_ + (size_t)tc * 128) * H_;
    for (int idx = tid; idx < 128 * 512; idx += 256){
      int r = idx >> 9;
      unsigned byteoff = ((unsigned)idx * 2u) ^ ((unsigned)(r & 7) << 4);
      enc_s[byteoff >> 1] = f2b(ep[idx]);
    }
  }
  { // init recurrent state: h0[1]=h1[1]=0, c0=c1=0, u[1]=0, Z[1]=1
    int gtid = bb * 256 + tid;
    if (gtid < 16384){
      P.h0[16384 + gtid] = 0.f; P.h1[16384 + gtid] = 0.f;
      P.c0[gtid] = 0.f; P.c1[gtid] = 0.f;
      P.u[16384 + gtid] = 0.f;
    }
    if (gtid < 32) P.Zb[32 + gtid] = 1.f;
  }
  grid.sync();

  const int bth = tid >> 3;            // batch 0..31
  const int sub = tid & 7;             // jl*4+q
  const int jl = sub >> 2, q = sub & 3;
  const int j2 = bb * 2 + jl;          // hidden idx 0..511
  const int g0 = q * 512 + j2;         // gate row 0..2047

  float myscore = 0.f;

  for (int t = 0; t < T_; ++t){
    const int p = t & 1, pp = p ^ 1;
    // ---------- S1: LSTM layer 0 ----------
    {
      if (tid < 64) P.u[p * 16384 + bb * 64 + tid] = 0.f;          // clear this step's u
      if (bb < 32 && tid == 64) P.Zb[p * 32 + bb] = 0.f;
      if (bb < 32 && tid == 65) P.smax[p * 32 + bb] = 0x007FFFFFu; // enc(-inf)
      const int tok = (t == 0) ? 1 : P.padded[bth * TO_ + (t - 1)]; // SOS=1
      const float* er = P.emb + (size_t)tok * H_;
      const float* wi = P.Wih0 + (size_t)g0 * 1024;
      const float* wh = P.Whh0 + (size_t)g0 * 512;
      const float* up = P.u + pp * 16384 + bth * 512;
      const float* hp = P.h0 + pp * 16384 + bth * 512;
      const float rZ = 1.f / P.Zb[pp * 32 + bth];
      f32x4 va = {0.f, 0.f, 0.f, 0.f};
      for (int k = 0; k < 512; k += 4){
        va += (*(const f32x4*)(er + k)) * (*(const f32x4*)(wi + k));
        va += ((*(const f32x4*)(up + k)) * rZ) * (*(const f32x4*)(wi + 512 + k));
        va += (*(const f32x4*)(hp + k)) * (*(const f32x4*)(wh + k));
      }
      float acc = P.bih0[g0] + P.bhh0[g0] + va.x + va.y + va.z + va.w;
      // store att_c(t-1) into mlpin (blocks 0..31 <-> batch)
      if (bb < 32 && t > 0){
        float rZb = 1.f / P.Zb[pp * 32 + bb];
        for (int h = tid; h < 512; h += 256)
          P.mlpin[((size_t)(t - 1) * B_ + bb) * 1024 + 512 + h] =
              f2b(P.u[pp * 16384 + bb * 512 + h] * rZb);
      }
      gate_s[bth][sub] = acc;
      __syncthreads();
      if (tid < 64){
        const int b2_ = tid >> 1, jj = bb * 2 + (tid & 1);
        const float* gs = gate_s[b2_] + (tid & 1) * 4;
        float ii = sigf(gs[0]), ff = sigf(gs[1]), gg = tanhf(gs[2]), oo = sigf(gs[3]);
        float c = ff * P.c0[b2_ * 512 + jj] + ii * gg;
        P.c0[b2_ * 512 + jj] = c;
        P.h0[p * 16384 + b2_ * 512 + jj] = oo * tanhf(c);
      }
    }
    grid.sync();
    // ---------- S2: LSTM layer 1 ----------
    {
      const float* wi = P.Wih1 + (size_t)g0 * 512;
      const float* wh = P.Whh1 + (size_t)g0 * 512;
      const float* h0n = P.h0 + p * 16384 + bth * 512;
      const float* h1p = P.h1 + pp * 16384 + bth * 512;
      f32x4 va = {0.f, 0.f, 0.f, 0.f};
      for (int k = 0; k < 512; k += 4){
        va += (*(const f32x4*)(h0n + k)) * (*(const f32x4*)(wi + k));
        va += (*(const f32x4*)(h1p + k)) * (*(const f32x4*)(wh + k));
      }
      float acc = P.bih1[g0] + P.bhh1[g0] + va.x + va.y + va.z + va.w;
      gate_s[bth][sub] = acc;
      __syncthreads();
      if (tid < 64){
        const int b2_ = tid >> 1, jj = bb * 2 + (tid & 1);
        const float* gs = gate_s[b2_] + (tid & 1) * 4;
        float ii = sigf(gs[0]), ff = sigf(gs[1]), gg = tanhf(gs[2]), oo = sigf(gs[3]);
        float c = ff * P.c1[b2_ * 512 + jj] + ii * gg;
        P.c1[b2_ * 512 + jj] = c;
        float hh = oo * tanhf(c);
        P.h1[p * 16384 + b2_ * 512 + jj] = hh;
        P.mlpin[((size_t)t * B_ + b2_) * 1024 + jj] = f2b(hh);
      }
    }
    grid.sync();
    // ---------- S3: attention scores + per-b max ----------
    {
      for (int h = tid; h < 512; h += 256)
        h1_s[h] = P.h1[p * 16384 + b_att * 512 + h];
      __syncthreads();
      const int ti_l = tid >> 1, half = tid & 1;
      float s = 0.f;
      const unsigned swz = (unsigned)(ti_l & 7) << 4;
      for (int h8 = half * 256; h8 < half * 256 + 256; h8 += 8){
        unsigned byteoff = ((unsigned)(ti_l * 512 + h8) * 2u) ^ swz;
        s16x8 ev = *(const s16x8*)((const char*)enc_s + byteoff);
        #pragma unroll
        for (int e = 0; e < 8; ++e) s += b2f((unsigned short)ev[e]) * h1_s[h8 + e];
      }
      s += __shfl_xor(s, 1);
      myscore = s;
      float m = s;
      #pragma unroll
      for (int off = 2; off < 64; off <<= 1) m = fmaxf(m, __shfl_xor(m, off));
      if ((tid & 63) == 0) atomicMax(P.smax + p * 32 + b_att, fenc(m));
    }
    grid.sync();
    // ---------- S4: softmax weights + unnormalized context partials ----------
    {
      const float m = fdec(P.smax[p * 32 + b_att]);
      const int ti_l = tid >> 1, half = tid & 1;
      if (half == 0) w_s[ti_l] = expf(myscore - m);
      __syncthreads();
      if (tid < 128){
        float z = w_s[tid];
        #pragma unroll
        for (int off = 1; off < 64; off <<= 1) z += __shfl_xor(z, off);
        if ((tid & 63) == 0) unsafeAtomicAdd(P.Zb + p * 32 + b_att, z);
      }
      float a0 = 0.f, a1 = 0.f;
      const int hc0 = tid, hc1 = tid + 256;
      for (int ti = 0; ti < 128; ++ti){
        const float wv = w_s[ti];
        const unsigned base = (unsigned)ti * 1024u;
        const unsigned sw = (unsigned)(ti & 7) << 4;
        a0 += wv * b2f(*(const unsigned short*)((const char*)enc_s + ((base + hc0 * 2) ^ sw)));
        a1 += wv * b2f(*(const unsigned short*)((const char*)enc_s + ((base + hc1 * 2) ^ sw)));
      }
      unsafeAtomicAdd(P.u + p * 16384 + b_att * 512 + hc0, a0);
      unsafeAtomicAdd(P.u + p * 16384 + b_att * 512 + hc1, a1);
    }
    grid.sync();
  }
  // att_c of final step
  if (bb < 32){
    const int p = (T_ - 1) & 1;
    float rZb = 1.f / P.Zb[p * 32 + bb];
    for (int h = tid; h < 512; h += 256)
      P.mlpin[((size_t)(T_ - 1) * B_ + bb) * 1024 + 512 + h] =
          f2b(P.u[p * 16384 + bb * 512 + h] * rZb);
  }
}

// ------------------------------------------------------------------
// B1: tanhv = tanh(mlpin @ W1^T + b1)   M=8224 N=512 K=1024, bf16 MFMA
__global__ __launch_bounds__(256) void kB1(Ptrs P){
  const int wid = blockIdx.x * 4 + (threadIdx.x >> 6);
  if (wid >= 129 * 8) return;
  const int mt = wid >> 3, nt = wid & 7;
  const int l = threadIdx.x & 63, lr = l & 15, lk = l >> 4;
  const int mr = mt * 64, nc = nt * 64;
  f32x4 acc[4][4] = {};
  for (int k0 = 0; k0 < 1024; k0 += 32){
    s16x8 af[4], bfm[4];
    #pragma unroll
    for (int f = 0; f < 4; ++f){
      int row = mr + f * 16 + lr; if (row > NROW_ - 1) row = NROW_ - 1;
      af[f] = *(const s16x8*)(P.mlpin + (size_t)row * 1024 + k0 + lk * 8);
      int col = nc + f * 16 + lr;
      bfm[f] = *(const s16x8*)(P.W1b + (size_t)col * 1024 + k0 + lk * 8);
    }
    #pragma unroll
    for (int fi = 0; fi < 4; ++fi)
      #pragma unroll
      for (int fj = 0; fj < 4; ++fj)
        acc[fi][fj] = __builtin_amdgcn_mfma_f32_16x16x32_bf16(af[fi], bfm[fj], acc[fi][fj], 0, 0, 0);
  }
  #pragma unroll
  for (int fi = 0; fi < 4; ++fi){
    #pragma unroll
    for (int jj = 0; jj < 4; ++jj){
      int m = mr + fi * 16 + lk * 4 + jj;
      if (m >= NROW_) continue;
      #pragma unroll
      for (int fj = 0; fj < 4; ++fj){
        int n = nc + fj * 16 + lr;
        P.tanhv[(size_t)m * 512 + n] = f2b(tanhf(acc[fi][fj][jj] + P.b1[n]));
      }
    }
  }
}

// B2: logits = tanhv @ W2^T + b2, fused exp-rowsum.  M=8224 N=10000 K=512
__global__ __launch_bounds__(256) void kB2(Ptrs P){
  const int wid = blockIdx.x * 4 + (threadIdx.x >> 6);
  if (wid >= 129 * 157) return;
  const int mt = wid / 157, nt = wid % 157;
  const int l = threadIdx.x & 63, lr = l & 15, lk = l >> 4;
  const int mr = mt * 64, nc = nt * 64;
  f32x4 acc[4][4] = {};
  for (int k0 = 0; k0 < 512; k0 += 32){
    s16x8 af[4], bfm[4];
    #pragma unroll
    for (int f = 0; f < 4; ++f){
      int row = mr + f * 16 + lr; if (row > NROW_ - 1) row = NROW_ - 1;
      af[f] = *(const s16x8*)(P.tanhv + (size_t)row * 512 + k0 + lk * 8);
      int col = nc + f * 16 + lr; if (col > V_ - 1) col = V_ - 1;
      bfm[f] = *(const s16x8*)(P.W2b + (size_t)col * 512 + k0 + lk * 8);
    }
    #pragma unroll
    for (int fi = 0; fi < 4; ++fi)
      #pragma unroll
      for (int fj = 0; fj < 4; ++fj)
        acc[fi][fj] = __builtin_amdgcn_mfma_f32_16x16x32_bf16(af[fi], bfm[fj], acc[fi][fj], 0, 0, 0);
  }
  #pragma unroll
  for (int fi = 0; fi < 4; ++fi){
    #pragma unroll
    for (int jj = 0; jj < 4; ++jj){
      const int m = mr + fi * 16 + lk * 4 + jj;
      float s = 0.f;
      #pragma unroll
      for (int fj = 0; fj < 4; ++fj){
        int n = nc + fj * 16 + lr;
        if (n < V_) s += expf(acc[fi][fj][jj] + P.b2[n]);
      }
      s += __shfl_xor(s, 1); s += __shfl_xor(s, 2);
      s += __shfl_xor(s, 4); s += __shfl_xor(s, 8);
      if (lr == 0 && m < NROW_) unsafeAtomicAdd(P.rowsum + m, s);
    }
  }
}

// label logit per row (one wave per row)
__global__ __launch_bounds__(256) void kL1(Ptrs P){
  const int wid = blockIdx.x * 4 + (threadIdx.x >> 6);
  if (wid >= NROW_) return;
  const int l = threadIdx.x & 63;
  const int t = wid >> 5, b = wid & 31;
  const int lab = (t < TO_) ? P.padded[b * TO_ + t] : 2;   // EOS=2
  float s = 0.f;
  s16x8 av = *(const s16x8*)(P.tanhv + (size_t)wid * 512 + l * 8);
  s16x8 wv = *(const s16x8*)(P.W2b + (size_t)lab * 512 + l * 8);
  #pragma unroll
  for (int e = 0; e < 8; ++e) s += b2f((unsigned short)av[e]) * b2f((unsigned short)wv[e]);
  #pragma unroll
  for (int off = 1; off < 64; off <<= 1) s += __shfl_xor(s, off);
  if (l == 0) P.lablog[wid] = s + P.b2[lab];
}

// final masked-NLL reduction
__global__ __launch_bounds__(512) void kL2(Ptrs P){
  __shared__ float ssum[8], scnt[8];
  const int tid = threadIdx.x;
  float sum = 0.f, cnt = 0.f;
  for (int r = tid; r < NROW_; r += 512){
    int t = r >> 5, b = r & 31;
    int lab = (t < TO_) ? P.padded[b * TO_ + t] : 2;
    if (lab != 0){ sum += logf(P.rowsum[r]) - P.lablog[r]; cnt += 1.f; }
  }
  #pragma unroll
  for (int off = 1; off < 64; off <<= 1){ sum += __shfl_xor(sum, off); cnt += __shfl_xor(cnt, off); }
  if ((tid & 63) == 0){ ssum[tid >> 6] = sum; scnt[tid >> 6] = cnt; }
  __syncthreads();
  if (tid == 0){
    float S = 0.f, C = 0.f;
    for (int i = 0; i < 8; ++i){ S += ssum[i]; C += scnt[i]; }
    P.out[0] = S / fmaxf(C, 1.f);
  }
}

// ------------------------------------------------------------------
extern "C" void kernel_launch(void* const* d_in, const int* in_sizes, int n_in,
                              void* d_out, int out_size, void* d_ws, size_t ws_size,
                              hipStream_t stream){
  (void)in_sizes; (void)n_in; (void)out_size; (void)ws_size;
  Ptrs P;
  P.padded = (const int*)d_in[0];
  P.enc    = (const float*)d_in[1];
  P.emb    = (const float*)d_in[2];
  P.Wih0 = (const float*)d_in[3];  P.Whh0 = (const float*)d_in[4];
  P.bih0 = (const float*)d_in[5];  P.bhh0 = (const float*)d_in[6];
  P.Wih1 = (const float*)d_in[7];  P.Whh1 = (const float*)d_in[8];
  P.bih1 = (const float*)d_in[9];  P.bhh1 = (const float*)d_in[10];
  P.W1 = (const float*)d_in[11];   P.b1 = (const float*)d_in[12];
  P.W2 = (const float*)d_in[13];   P.b2 = (const float*)d_in[14];
  P.out = (float*)d_out;

  char* w = (char*)d_ws;
  size_t off = 0;
  auto take = [&](size_t bytes) -> void* {
    void* ptr = (void*)(w + off);
    off += (bytes + 255) & ~(size_t)255;
    return ptr;
  };
  P.mlpin  = (unsigned short*)take((size_t)T_ * B_ * 1024 * 2);
  P.tanhv  = (unsigned short*)take((size_t)NROW_ * 512 * 2);
  P.W1b    = (unsigned short*)take((size_t)512 * 1024 * 2);
  P.W2b    = (unsigned short*)take((size_t)V_ * 512 * 2);
  P.h0     = (float*)take(2 * 32 * 512 * 4);
  P.h1     = (float*)take(2 * 32 * 512 * 4);
  P.c0     = (float*)take(32 * 512 * 4);
  P.c1     = (float*)take(32 * 512 * 4);
  P.u      = (float*)take(2 * 32 * 512 * 4);
  P.Zb     = (float*)take(2 * 32 * 4);
  P.smax   = (unsigned*)take(2 * 32 * 4);
  P.rowsum = (float*)take(NROW_ * 4);
  P.lablog = (float*)take(NROW_ * 4);

  kprep<<<dim3(1024), dim3(256), 0, stream>>>(P);
  void* args[] = { (void*)&P };
  hipLaunchCooperativeKernel(kA, dim3(256), dim3(256), args, 0, stream);
  kB1<<<dim3(258),  dim3(256), 0, stream>>>(P);
  kB2<<<dim3(5064), dim3(256), 0, stream>>>(P);
  kL1<<<dim3(2056), dim3(256), 0, stream>>>(P);
  kL2<<<dim3(1),    dim3(512), 0, stream>>>(P);
}

// Round 2
// 15438.672 us; speedup vs baseline: 3.8169x; 3.8169x over previous
//
#include <hip/hip_runtime.h>
#include <hip/hip_bf16.h>

// Problem constants
#define B_    32
#define TO_   256
#define T_    257        // To+1 decode steps
#define H_    512
#define V_    10000
#define TI_   1024
#define NROW_ 8224       // T_*B_
#define NB_   256        // blocks in cooperative kernel

using f32x4 = __attribute__((ext_vector_type(4))) float;
using s16x8 = __attribute__((ext_vector_type(8))) short;

struct Ptrs {
  const int* padded;
  const float* enc;
  const float* emb;
  const float *Wih0, *Whh0, *bih0, *bhh0;
  const float *Wih1, *Whh1, *bih1, *bhh1;
  const float *W1, *b1, *W2, *b2;
  float* out;
  // workspace
  unsigned short *mlpin;   // [257][32][1024] bf16  (=[h1 | att_c])
  unsigned short *embt;    // [257][32][512] bf16 embedded tokens; tanhv overlays after kA
  unsigned short *tanhv;   // [8224][512] bf16 (== embt region)
  unsigned short *W0c;     // [2048][1536] bf16, row g'=j*4+q = [Wih0row | Whh0row]; W2b overlays
  unsigned short *W1c;     // [2048][1024] bf16, row g'=j*4+q = [Wih1row | Whh1row]
  unsigned short *W1b;     // [512][1024] bf16
  unsigned short *W2b;     // [10000][512] bf16 (== W0c region, filled by kprep2)
  float *bias0c, *bias1c;  // [2048] combined biases, gate-interleaved
  float *u;                // [2][32][512] unnormalized context (atomicAdd)
  unsigned short *Xh0;     // [2][32][512] bf16 h0 state
  unsigned short *Xh1;     // [2][32][512] bf16 h1 state
  float *Xh1f;             // [2][32][512] f32 h1 state (attention)
  float *Zb;               // [2][32] softmax denominators
  unsigned *bar;           // [2] barrier counter+generation
  float *rowsum;           // [8224]
  float *lablog;           // [8224]
};

__device__ __forceinline__ unsigned short f2b(float f){
  __hip_bfloat16 h = __float2bfloat16(f);
  unsigned short r; __builtin_memcpy(&r, &h, 2); return r;
}
__device__ __forceinline__ float b2f(unsigned short u){
  unsigned v = ((unsigned)u) << 16; float f; __builtin_memcpy(&f, &v, 4); return f;
}
__device__ __forceinline__ float sigf(float x){ return 1.f / (1.f + expf(-x)); }

// ---- agent-scope (device) relaxed atomics: bypass non-coherent L1/L2 ----
__device__ __forceinline__ float aldf(const float* p){
  return __hip_atomic_load(p, __ATOMIC_RELAXED, __HIP_MEMORY_SCOPE_AGENT);
}
__device__ __forceinline__ unsigned long long aldu(const unsigned long long* p){
  return __hip_atomic_load(p, __ATOMIC_RELAXED, __HIP_MEMORY_SCOPE_AGENT);
}
__device__ __forceinline__ void astf(float* p, float v){
  __hip_atomic_store(p, v, __ATOMIC_RELAXED, __HIP_MEMORY_SCOPE_AGENT);
}
__device__ __forceinline__ void astu(unsigned long long* p, unsigned long long v){
  __hip_atomic_store(p, v, __ATOMIC_RELAXED, __HIP_MEMORY_SCOPE_AGENT);
}
__device__ __forceinline__ void astw(unsigned* p, unsigned v){
  __hip_atomic_store(p, v, __ATOMIC_RELAXED, __HIP_MEMORY_SCOPE_AGENT);
}

// custom grid barrier: no L2 flush. All cross-block data travels via agent
// atomics (L3), so only vmcnt-drain ordering is needed.
__device__ __forceinline__ void gbar(unsigned* bar){
  asm volatile("s_waitcnt vmcnt(0)" ::: "memory");   // all my stores at L3
  __syncthreads();
  if (threadIdx.x == 0){
    unsigned g = __hip_atomic_load(bar + 1, __ATOMIC_RELAXED, __HIP_MEMORY_SCOPE_AGENT);
    asm volatile("s_waitcnt vmcnt(0)" ::: "memory"); // g read before arrive visible
    unsigned a = __hip_atomic_fetch_add(bar, 1u, __ATOMIC_RELAXED, __HIP_MEMORY_SCOPE_AGENT);
    if (a == NB_ - 1u){
      __hip_atomic_store(bar, 0u, __ATOMIC_RELAXED, __HIP_MEMORY_SCOPE_AGENT);
      asm volatile("s_waitcnt vmcnt(0)" ::: "memory"); // reset visible before gen flip
      __hip_atomic_store(bar + 1, g + 1u, __ATOMIC_RELAXED, __HIP_MEMORY_SCOPE_AGENT);
    } else {
      unsigned cur;
      do {
        __builtin_amdgcn_s_sleep(2);
        cur = __hip_atomic_load(bar + 1, __ATOMIC_RELAXED, __HIP_MEMORY_SCOPE_AGENT);
      } while (cur == g);
    }
  }
  __syncthreads();
}

// ------------------------------------------------------------------
// prep: build embt, W0c/W1c (+combined biases), W1b; zero rowsum; init bar.
__global__ __launch_bounds__(256) void kprep(Ptrs P){
  const int stride = gridDim.x * blockDim.x;
  const int i0 = blockIdx.x * blockDim.x + threadIdx.x;
  if (i0 == 0){ P.bar[0] = 0u; P.bar[1] = 0u; }
  // embt[t][b][k]
  for (int i = i0; i < T_ * B_ * 512; i += stride){
    int k = i & 511, tb = i >> 9, b = tb & 31, t = tb >> 5;
    int tok = (t == 0) ? 1 : P.padded[b * TO_ + (t - 1)];
    P.embt[i] = f2b(P.emb[(size_t)tok * 512 + k]);
  }
  // W0c[g'][k], g'=j*4+q, k<1024: Wih0[q*512+j][k], else Whh0[q*512+j][k-1024]
  for (int i = i0; i < 2048 * 1536; i += stride){
    int k = i % 1536, gp = i / 1536;
    int j = gp >> 2, q = gp & 3, g = q * 512 + j;
    float v = (k < 1024) ? P.Wih0[(size_t)g * 1024 + k] : P.Whh0[(size_t)g * 512 + (k - 1024)];
    P.W0c[i] = f2b(v);
  }
  for (int i = i0; i < 2048 * 1024; i += stride){
    int k = i & 1023, gp = i >> 10;
    int j = gp >> 2, q = gp & 3, g = q * 512 + j;
    float v = (k < 512) ? P.Wih1[(size_t)g * 512 + k] : P.Whh1[(size_t)g * 512 + (k - 512)];
    P.W1c[i] = f2b(v);
  }
  for (int i = i0; i < 2048; i += stride){
    int j = i >> 2, q = i & 3, g = q * 512 + j;
    P.bias0c[i] = P.bih0[g] + P.bhh0[g];
    P.bias1c[i] = P.bih1[g] + P.bhh1[g];
  }
  for (int i = i0; i < 512 * 1024; i += stride) P.W1b[i] = f2b(P.W1[i]);
  for (int i = i0; i < NROW_; i += stride) P.rowsum[i] = 0.f;
}

// kprep2 (after kA): W2 -> bf16, overlaying the dead W0c/W1c region
__global__ __launch_bounds__(256) void kprep2(Ptrs P){
  const int stride = gridDim.x * blockDim.x;
  const int i0 = blockIdx.x * blockDim.x + threadIdx.x;
  for (int i = i0; i < V_ * 512; i += stride) P.W2b[i] = f2b(P.W2[i]);
}

// ------------------------------------------------------------------
// Phase A: persistent cooperative recurrence, custom barrier, MFMA LSTM gates.
// Roles per phase:
//   S1: bb<128 GEMM layer0 (n-tile of 16 gates) ; bb in [128,160): mlpin att_c(t-1)
//   S2: bb<128 GEMM layer1 ; bb in [160,224): clear u[pp] ; bb==224: clear Zb[pp]
//   S34: all 256 blocks: attention (b_att=bb>>3, ti-chunk=(bb&7)*128)
__global__ __launch_bounds__(256, 1) void kA(Ptrs P){
  __shared__ __align__(16) unsigned short enc_s[128 * 512]; // 128 KB, XOR-swizzled
  __shared__ float h1_s[512];
  __shared__ float w_s[128];
  __shared__ float gate_s[32][17];
  __shared__ float h_s[32][4];
  const int bb = blockIdx.x, tid = threadIdx.x;
  const int b_att = bb >> 3;

  { // stage encoder slice -> LDS bf16 with byte^=((row&7)<<4) swizzle
    const float* ep = P.enc + ((size_t)b_att * TI_ + (size_t)(bb & 7) * 128) * H_;
    for (int idx = tid; idx < 128 * 512; idx += 256){
      int r = idx >> 9;
      unsigned byteoff = ((unsigned)idx * 2u) ^ ((unsigned)(r & 7) << 4);
      enc_s[byteoff >> 1] = f2b(ep[idx]);
    }
  }
  { // init state via agent atomics
    int g = bb * 256 + tid;                    // 0..65535
    if (g < 32768){ astf(P.u + g, 0.f); astf(P.Xh1f + g, 0.f); }
    if (g < 16384){ astw((unsigned*)P.Xh0 + g, 0u); astw((unsigned*)P.Xh1 + g, 0u); }
    if (g < 64) astf(P.Zb + g, (g >= 32) ? 1.f : 0.f);
  }
  gbar(P.bar);

  const int wv = tid >> 6;              // wave id
  const int l  = tid & 63, lr = l & 15, lk = l >> 4;
  const int eidx = tid - 128;           // epilogue index (tid>=128)
  const int eb = eidx >> 2, ejl = eidx & 3;
  float c0r = 0.f, c1r = 0.f;           // cell state (threads 128..255)

  for (int t = 0; t < T_; ++t){
    const int p = t & 1, pp = p ^ 1;
    // ================= S1: LSTM layer 0 =================
    if (bb < 128){
      if (wv < 2){
        const int batch = wv * 16 + lr;
        const unsigned short* Brow = P.W0c + (size_t)(bb * 16 + lr) * 1536;
        const unsigned short* Erow = P.embt + ((size_t)t * 32 + batch) * 512;
        const float* Urow = P.u + pp * 16384 + batch * 512;
        const unsigned long long* Hrow =
            (const unsigned long long*)(P.Xh0 + pp * 16384 + batch * 512);
        const float rZ = 1.f / aldf(P.Zb + pp * 32 + batch);
        f32x4 acc = {0.f, 0.f, 0.f, 0.f};
        #pragma unroll
        for (int ks = 0; ks < 16; ++ks){            // e-segment (plain, L2)
          s16x8 a = *(const s16x8*)(Erow + ks * 32 + lk * 8);
          s16x8 b = *(const s16x8*)(Brow + ks * 32 + lk * 8);
          acc = __builtin_amdgcn_mfma_f32_16x16x32_bf16(a, b, acc, 0, 0, 0);
        }
        #pragma unroll
        for (int ks = 0; ks < 16; ++ks){            // att_c segment (u * rZ)
          const int kb = ks * 32 + lk * 8;
          unsigned long long dd[4];
          dd[0] = aldu((const unsigned long long*)(Urow + kb));
          dd[1] = aldu((const unsigned long long*)(Urow + kb + 2));
          dd[2] = aldu((const unsigned long long*)(Urow + kb + 4));
          dd[3] = aldu((const unsigned long long*)(Urow + kb + 6));
          float uf[8]; __builtin_memcpy(uf, dd, 32);
          s16x8 a;
          #pragma unroll
          for (int e = 0; e < 8; ++e) a[e] = (short)f2b(uf[e] * rZ);
          s16x8 b = *(const s16x8*)(Brow + 512 + kb);
          acc = __builtin_amdgcn_mfma_f32_16x16x32_bf16(a, b, acc, 0, 0, 0);
        }
        #pragma unroll
        for (int ks = 0; ks < 16; ++ks){            // h0_prev segment (bf16)
          const int kb = ks * 32 + lk * 8;
          unsigned long long dd[2];
          dd[0] = aldu(Hrow + (kb >> 2));
          dd[1] = aldu(Hrow + (kb >> 2) + 1);
          s16x8 a; __builtin_memcpy(&a, dd, 16);
          s16x8 b = *(const s16x8*)(Brow + 1024 + kb);
          acc = __builtin_amdgcn_mfma_f32_16x16x32_bf16(a, b, acc, 0, 0, 0);
        }
        #pragma unroll
        for (int j = 0; j < 4; ++j) gate_s[wv * 16 + lk * 4 + j][lr] = acc[j];
      }
    } else if (bb < 160 && t > 0){
      // write mlpin att_c(t-1) for batch b = bb-128
      const int b = bb - 128;
      const float rZ = 1.f / aldf(P.Zb + pp * 32 + b);
      unsigned long long v = aldu((const unsigned long long*)(P.u + pp * 16384 + b * 512) + tid);
      float f2[2]; __builtin_memcpy(f2, &v, 8);
      unsigned pk = (unsigned)f2b(f2[0] * rZ) | ((unsigned)f2b(f2[1] * rZ) << 16);
      *(unsigned*)(P.mlpin + ((size_t)(t - 1) * 32 + b) * 1024 + 512 + tid * 2) = pk;
    }
    __syncthreads();
    if (bb < 128 && tid >= 128){
      const float* bs = P.bias0c + bb * 16 + ejl * 4;
      float ii = sigf (gate_s[eb][ejl * 4 + 0] + bs[0]);
      float ff = sigf (gate_s[eb][ejl * 4 + 1] + bs[1]);
      float gg = tanhf(gate_s[eb][ejl * 4 + 2] + bs[2]);
      float oo = sigf (gate_s[eb][ejl * 4 + 3] + bs[3]);
      float cn = ff * c0r + ii * gg; c0r = cn;
      h_s[eb][ejl] = oo * tanhf(cn);
    }
    __syncthreads();
    if (bb < 128 && tid < 32){
      unsigned short hb[4];
      #pragma unroll
      for (int jl = 0; jl < 4; ++jl) hb[jl] = f2b(h_s[tid][jl]);
      unsigned long long v; __builtin_memcpy(&v, hb, 8);
      astu((unsigned long long*)(P.Xh0 + p * 16384 + tid * 512 + bb * 4), v);
    }
    gbar(P.bar);
    // ================= S2: LSTM layer 1 =================
    if (bb < 128){
      if (wv < 2){
        const int batch = wv * 16 + lr;
        const unsigned short* Brow = P.W1c + (size_t)(bb * 16 + lr) * 1024;
        const unsigned long long* H0r =
            (const unsigned long long*)(P.Xh0 + p * 16384 + batch * 512);
        const unsigned long long* H1r =
            (const unsigned long long*)(P.Xh1 + pp * 16384 + batch * 512);
        f32x4 acc = {0.f, 0.f, 0.f, 0.f};
        #pragma unroll
        for (int ks = 0; ks < 16; ++ks){            // h0(t) segment
          const int kb = ks * 32 + lk * 8;
          unsigned long long dd[2];
          dd[0] = aldu(H0r + (kb >> 2));
          dd[1] = aldu(H0r + (kb >> 2) + 1);
          s16x8 a; __builtin_memcpy(&a, dd, 16);
          s16x8 b = *(const s16x8*)(Brow + kb);
          acc = __builtin_amdgcn_mfma_f32_16x16x32_bf16(a, b, acc, 0, 0, 0);
        }
        #pragma unroll
        for (int ks = 0; ks < 16; ++ks){            // h1(t-1) segment
          const int kb = ks * 32 + lk * 8;
          unsigned long long dd[2];
          dd[0] = aldu(H1r + (kb >> 2));
          dd[1] = aldu(H1r + (kb >> 2) + 1);
          s16x8 a; __builtin_memcpy(&a, dd, 16);
          s16x8 b = *(const s16x8*)(Brow + 512 + kb);
          acc = __builtin_amdgcn_mfma_f32_16x16x32_bf16(a, b, acc, 0, 0, 0);
        }
        #pragma unroll
        for (int j = 0; j < 4; ++j) gate_s[wv * 16 + lk * 4 + j][lr] = acc[j];
      }
    } else if (bb < 224){
      astf(P.u + pp * 16384 + (bb - 160) * 256 + tid, 0.f);  // clear u[pp]
    } else if (bb == 224 && tid < 32){
      astf(P.Zb + pp * 32 + tid, 0.f);
    }
    __syncthreads();
    if (bb < 128 && tid >= 128){
      const float* bs = P.bias1c + bb * 16 + ejl * 4;
      float ii = sigf (gate_s[eb][ejl * 4 + 0] + bs[0]);
      float ff = sigf (gate_s[eb][ejl * 4 + 1] + bs[1]);
      float gg = tanhf(gate_s[eb][ejl * 4 + 2] + bs[2]);
      float oo = sigf (gate_s[eb][ejl * 4 + 3] + bs[3]);
      float cn = ff * c1r + ii * gg; c1r = cn;
      h_s[eb][ejl] = oo * tanhf(cn);
    }
    __syncthreads();
    if (bb < 128 && tid < 32){
      unsigned short hb[4];
      #pragma unroll
      for (int jl = 0; jl < 4; ++jl) hb[jl] = f2b(h_s[tid][jl]);
      unsigned long long vb; __builtin_memcpy(&vb, hb, 8);
      astu((unsigned long long*)(P.Xh1 + p * 16384 + tid * 512 + bb * 4), vb);
      *(unsigned long long*)(P.mlpin + ((size_t)t * 32 + tid) * 1024 + bb * 4) = vb;
      unsigned long long w0, w1;
      __builtin_memcpy(&w0, &h_s[tid][0], 8);
      __builtin_memcpy(&w1, &h_s[tid][2], 8);
      unsigned long long* dst = (unsigned long long*)P.Xh1f + ((p * 16384 + tid * 512 + bb * 4) >> 1);
      astu(dst, w0); astu(dst + 1, w1);
    }
    gbar(P.bar);
    // ================= S34: attention (scores+softmax+context) =================
    {
      unsigned long long v = aldu((const unsigned long long*)(P.Xh1f + p * 16384 + b_att * 512) + tid);
      float f2[2]; __builtin_memcpy(f2, &v, 8);
      h1_s[tid * 2] = f2[0]; h1_s[tid * 2 + 1] = f2[1];
    }
    __syncthreads();
    {
      const int ti_l = tid >> 1, half = tid & 1;
      float s = 0.f;
      const unsigned swz = (unsigned)(ti_l & 7) << 4;
      for (int h8 = half * 256; h8 < half * 256 + 256; h8 += 8){
        unsigned byteoff = ((unsigned)(ti_l * 512 + h8) * 2u) ^ swz;
        s16x8 ev = *(const s16x8*)((const char*)enc_s + byteoff);
        #pragma unroll
        for (int e = 0; e < 8; ++e) s += b2f((unsigned short)ev[e]) * h1_s[h8 + e];
      }
      s += __shfl_xor(s, 1);
      if (half == 0) w_s[ti_l] = expf(s);       // no max-shift: |s| << 88
    }
    __syncthreads();
    {
      if (tid < 128){
        float z = w_s[tid];
        #pragma unroll
        for (int off = 1; off < 64; off <<= 1) z += __shfl_xor(z, off);
        if ((tid & 63) == 0) unsafeAtomicAdd(P.Zb + p * 32 + b_att, z);
      }
      float a0 = 0.f, a1 = 0.f;
      const int hc0 = tid, hc1 = tid + 256;
      for (int ti = 0; ti < 128; ++ti){
        const float wvv = w_s[ti];
        const unsigned base = (unsigned)ti * 1024u;
        const unsigned sw = (unsigned)(ti & 7) << 4;
        a0 += wvv * b2f(*(const unsigned short*)((const char*)enc_s + ((base + hc0 * 2) ^ sw)));
        a1 += wvv * b2f(*(const unsigned short*)((const char*)enc_s + ((base + hc1 * 2) ^ sw)));
      }
      unsafeAtomicAdd(P.u + p * 16384 + b_att * 512 + hc0, a0);
      unsafeAtomicAdd(P.u + p * 16384 + b_att * 512 + hc1, a1);
    }
    gbar(P.bar);
  }
  // final att_c (t=256, p=0)
  if (bb >= 128 && bb < 160){
    const int b = bb - 128;
    const float rZ = 1.f / aldf(P.Zb + 0 * 32 + b);
    unsigned long long v = aldu((const unsigned long long*)(P.u + 0 * 16384 + b * 512) + tid);
    float f2[2]; __builtin_memcpy(f2, &v, 8);
    unsigned pk = (unsigned)f2b(f2[0] * rZ) | ((unsigned)f2b(f2[1] * rZ) << 16);
    *(unsigned*)(P.mlpin + ((size_t)256 * 32 + b) * 1024 + 512 + tid * 2) = pk;
  }
}

// ------------------------------------------------------------------
// B1: tanhv = tanh(mlpin @ W1^T + b1)   M=8224 N=512 K=1024, bf16 MFMA
__global__ __launch_bounds__(256) void kB1(Ptrs P){
  const int wid = blockIdx.x * 4 + (threadIdx.x >> 6);
  if (wid >= 129 * 8) return;
  const int mt = wid >> 3, nt = wid & 7;
  const int l = threadIdx.x & 63, lr = l & 15, lk = l >> 4;
  const int mr = mt * 64, nc = nt * 64;
  f32x4 acc[4][4] = {};
  for (int k0 = 0; k0 < 1024; k0 += 32){
    s16x8 af[4], bfm[4];
    #pragma unroll
    for (int f = 0; f < 4; ++f){
      int row = mr + f * 16 + lr; if (row > NROW_ - 1) row = NROW_ - 1;
      af[f] = *(const s16x8*)(P.mlpin + (size_t)row * 1024 + k0 + lk * 8);
      int col = nc + f * 16 + lr;
      bfm[f] = *(const s16x8*)(P.W1b + (size_t)col * 1024 + k0 + lk * 8);
    }
    #pragma unroll
    for (int fi = 0; fi < 4; ++fi)
      #pragma unroll
      for (int fj = 0; fj < 4; ++fj)
        acc[fi][fj] = __builtin_amdgcn_mfma_f32_16x16x32_bf16(af[fi], bfm[fj], acc[fi][fj], 0, 0, 0);
  }
  #pragma unroll
  for (int fi = 0; fi < 4; ++fi){
    #pragma unroll
    for (int jj = 0; jj < 4; ++jj){
      int m = mr + fi * 16 + lk * 4 + jj;
      if (m >= NROW_) continue;
      #pragma unroll
      for (int fj = 0; fj < 4; ++fj){
        int n = nc + fj * 16 + lr;
        P.tanhv[(size_t)m * 512 + n] = f2b(tanhf(acc[fi][fj][jj] + P.b1[n]));
      }
    }
  }
}

// B2: logits = tanhv @ W2^T + b2, fused exp-rowsum.  M=8224 N=10000 K=512
__global__ __launch_bounds__(256) void kB2(Ptrs P){
  const int wid = blockIdx.x * 4 + (threadIdx.x >> 6);
  if (wid >= 129 * 157) return;
  const int mt = wid / 157, nt = wid % 157;
  const int l = threadIdx.x & 63, lr = l & 15, lk = l >> 4;
  const int mr = mt * 64, nc = nt * 64;
  f32x4 acc[4][4] = {};
  for (int k0 = 0; k0 < 512; k0 += 32){
    s16x8 af[4], bfm[4];
    #pragma unroll
    for (int f = 0; f < 4; ++f){
      int row = mr + f * 16 + lr; if (row > NROW_ - 1) row = NROW_ - 1;
      af[f] = *(const s16x8*)(P.tanhv + (size_t)row * 512 + k0 + lk * 8);
      int col = nc + f * 16 + lr; if (col > V_ - 1) col = V_ - 1;
      bfm[f] = *(const s16x8*)(P.W2b + (size_t)col * 512 + k0 + lk * 8);
    }
    #pragma unroll
    for (int fi = 0; fi < 4; ++fi)
      #pragma unroll
      for (int fj = 0; fj < 4; ++fj)
        acc[fi][fj] = __builtin_amdgcn_mfma_f32_16x16x32_bf16(af[fi], bfm[fj], acc[fi][fj], 0, 0, 0);
  }
  #pragma unroll
  for (int fi = 0; fi < 4; ++fi){
    #pragma unroll
    for (int jj = 0; jj < 4; ++jj){
      const int m = mr + fi * 16 + lk * 4 + jj;
      float s = 0.f;
      #pragma unroll
      for (int fj = 0; fj < 4; ++fj){
        int n = nc + fj * 16 + lr;
        if (n < V_) s += expf(acc[fi][fj][jj] + P.b2[n]);
      }
      s += __shfl_xor(s, 1); s += __shfl_xor(s, 2);
      s += __shfl_xor(s, 4); s += __shfl_xor(s, 8);
      if (lr == 0 && m < NROW_) unsafeAtomicAdd(P.rowsum + m, s);
    }
  }
}

// label logit per row (one wave per row)
__global__ __launch_bounds__(256) void kL1(Ptrs P){
  const int wid = blockIdx.x * 4 + (threadIdx.x >> 6);
  if (wid >= NROW_) return;
  const int l = threadIdx.x & 63;
  const int t = wid >> 5, b = wid & 31;
  const int lab = (t < TO_) ? P.padded[b * TO_ + t] : 2;   // EOS=2
  float s = 0.f;
  s16x8 av = *(const s16x8*)(P.tanhv + (size_t)wid * 512 + l * 8);
  s16x8 wv = *(const s16x8*)(P.W2b + (size_t)lab * 512 + l * 8);
  #pragma unroll
  for (int e = 0; e < 8; ++e) s += b2f((unsigned short)av[e]) * b2f((unsigned short)wv[e]);
  #pragma unroll
  for (int off = 1; off < 64; off <<= 1) s += __shfl_xor(s, off);
  if (l == 0) P.lablog[wid] = s + P.b2[lab];
}

// final masked-NLL reduction
__global__ __launch_bounds__(512) void kL2(Ptrs P){
  __shared__ float ssum[8], scnt[8];
  const int tid = threadIdx.x;
  float sum = 0.f, cnt = 0.f;
  for (int r = tid; r < NROW_; r += 512){
    int t = r >> 5, b = r & 31;
    int lab = (t < TO_) ? P.padded[b * TO_ + t] : 2;
    if (lab != 0){ sum += logf(P.rowsum[r]) - P.lablog[r]; cnt += 1.f; }
  }
  #pragma unroll
  for (int off = 1; off < 64; off <<= 1){ sum += __shfl_xor(sum, off); cnt += __shfl_xor(cnt, off); }
  if ((tid & 63) == 0){ ssum[tid >> 6] = sum; scnt[tid >> 6] = cnt; }
  __syncthreads();
  if (tid == 0){
    float S = 0.f, C = 0.f;
    for (int i = 0; i < 8; ++i){ S += ssum[i]; C += scnt[i]; }
    P.out[0] = S / fmaxf(C, 1.f);
  }
}

// ------------------------------------------------------------------
extern "C" void kernel_launch(void* const* d_in, const int* in_sizes, int n_in,
                              void* d_out, int out_size, void* d_ws, size_t ws_size,
                              hipStream_t stream){
  (void)in_sizes; (void)n_in; (void)out_size; (void)ws_size;
  Ptrs P;
  P.padded = (const int*)d_in[0];
  P.enc    = (const float*)d_in[1];
  P.emb    = (const float*)d_in[2];
  P.Wih0 = (const float*)d_in[3];  P.Whh0 = (const float*)d_in[4];
  P.bih0 = (const float*)d_in[5];  P.bhh0 = (const float*)d_in[6];
  P.Wih1 = (const float*)d_in[7];  P.Whh1 = (const float*)d_in[8];
  P.bih1 = (const float*)d_in[9];  P.bhh1 = (const float*)d_in[10];
  P.W1 = (const float*)d_in[11];   P.b1 = (const float*)d_in[12];
  P.W2 = (const float*)d_in[13];   P.b2 = (const float*)d_in[14];
  P.out = (float*)d_out;

  char* w = (char*)d_ws;
  size_t off = 0;
  auto take = [&](size_t bytes) -> void* {
    void* ptr = (void*)(w + off);
    off += (bytes + 255) & ~(size_t)255;
    return ptr;
  };
  P.mlpin  = (unsigned short*)take((size_t)T_ * B_ * 1024 * 2);   // 16.84 MB
  P.embt   = (unsigned short*)take((size_t)T_ * B_ * 512 * 2);    // 8.42 MB
  P.tanhv  = P.embt;                                              // overlay (post-kA)
  P.W0c    = (unsigned short*)take((size_t)2048 * 1536 * 2);      // 6.29 MB
  P.W1c    = (unsigned short*)take((size_t)2048 * 1024 * 2);      // 4.19 MB
  P.W2b    = P.W0c;                                               // overlay (post-kA)
  P.W1b    = (unsigned short*)take((size_t)512 * 1024 * 2);       // 1.05 MB
  P.bias0c = (float*)take(2048 * 4);
  P.bias1c = (float*)take(2048 * 4);
  P.u      = (float*)take(2 * 32 * 512 * 4);
  P.Xh0    = (unsigned short*)take(2 * 32 * 512 * 2);
  P.Xh1    = (unsigned short*)take(2 * 32 * 512 * 2);
  P.Xh1f   = (float*)take(2 * 32 * 512 * 4);
  P.Zb     = (float*)take(2 * 32 * 4);
  P.bar    = (unsigned*)take(256);
  P.rowsum = (float*)take(NROW_ * 4);
  P.lablog = (float*)take(NROW_ * 4);

  kprep<<<dim3(2048), dim3(256), 0, stream>>>(P);
  void* args[] = { (void*)&P };
  hipLaunchCooperativeKernel(kA, dim3(NB_), dim3(256), args, 0, stream);
  kprep2<<<dim3(1024), dim3(256), 0, stream>>>(P);
  kB1<<<dim3(258),  dim3(256), 0, stream>>>(P);
  kB2<<<dim3(5064), dim3(256), 0, stream>>>(P);
  kL1<<<dim3(2056), dim3(256), 0, stream>>>(P);
  kL2<<<dim3(1),    dim3(512), 0, stream>>>(P);
}

// Round 3
// 9489.594 us; speedup vs baseline: 6.2098x; 1.6269x over previous
//
#include <hip/hip_runtime.h>
#include <hip/hip_bf16.h>

// Problem constants
#define B_    32
#define TO_   256
#define T_    257        // To+1 decode steps
#define H_    512
#define V_    10000
#define TI_   1024
#define NROW_ 8224       // T_*B_
#define NB_   256        // blocks in cooperative kernel

using f32x4 = __attribute__((ext_vector_type(4))) float;
using s16x8 = __attribute__((ext_vector_type(8))) short;

struct Ptrs {
  const int* padded;
  const float* enc;
  const float* emb;
  const float *Wih0, *Whh0, *bih0, *bhh0;
  const float *Wih1, *Whh1, *bih1, *bhh1;
  const float *W1, *b1, *W2, *b2;
  float* out;
  // workspace
  unsigned short *mlpin;   // [257][32][1024] bf16  (=[h1 | att_c])
  unsigned short *embt;    // [257][32][512] bf16 embedded tokens; tanhv overlays after kA
  unsigned short *tanhv;   // [8224][512] bf16 (== embt region)
  unsigned short *W0c;     // [2048][1536] bf16, row g'=j*4+q = [Wih0row | Whh0row]; W2b overlays
  unsigned short *W1c;     // [2048][1024] bf16, row g'=j*4+q = [Wih1row | Whh1row]
  unsigned short *W1b;     // [512][1024] bf16
  unsigned short *W2b;     // [10000][512] bf16 (== W0c region, filled by kprep2)
  float *bias0c, *bias1c;  // [2048] combined biases, gate-interleaved
  float *u;                // [2][32][512] unnormalized context (atomicAdd)
  unsigned short *Xh0;     // [2][32][512] bf16 h0 state
  unsigned short *Xh1;     // [2][32][512] bf16 h1 state
  float *Xh1f;             // [2][32][512] f32 h1 state (attention)
  float *Zb;               // [2][32] softmax denominators
  unsigned *bar;           // tree barrier region (8 KB)
  float *rowsum;           // [8224]
  float *lablog;           // [8224]
};

__device__ __forceinline__ unsigned short f2b(float f){
  __hip_bfloat16 h = __float2bfloat16(f);
  unsigned short r; __builtin_memcpy(&r, &h, 2); return r;
}
__device__ __forceinline__ float b2f(unsigned short u){
  unsigned v = ((unsigned)u) << 16; float f; __builtin_memcpy(&f, &v, 4); return f;
}
__device__ __forceinline__ float sigf(float x){ return 1.f / (1.f + expf(-x)); }

// ---- agent-scope (device) relaxed atomics: bypass non-coherent L1/L2 ----
__device__ __forceinline__ float aldf(const float* p){
  return __hip_atomic_load(p, __ATOMIC_RELAXED, __HIP_MEMORY_SCOPE_AGENT);
}
__device__ __forceinline__ unsigned long long aldu(const unsigned long long* p){
  return __hip_atomic_load(p, __ATOMIC_RELAXED, __HIP_MEMORY_SCOPE_AGENT);
}
__device__ __forceinline__ void astf(float* p, float v){
  __hip_atomic_store(p, v, __ATOMIC_RELAXED, __HIP_MEMORY_SCOPE_AGENT);
}
__device__ __forceinline__ void astu(unsigned long long* p, unsigned long long v){
  __hip_atomic_store(p, v, __ATOMIC_RELAXED, __HIP_MEMORY_SCOPE_AGENT);
}
__device__ __forceinline__ void astw(unsigned* p, unsigned v){
  __hip_atomic_store(p, v, __ATOMIC_RELAXED, __HIP_MEMORY_SCOPE_AGENT);
}

// Two-level tree barrier, no L2 flush. Layout in bar[] (uint units):
//   grpCnt[g] @ g*64 (g=0..7, 256B apart) ; rootCnt @ 512 ; gen[g] @ (16+g)*64
// ph is a monotonically increasing phase id (starts at 1; region zeroed by kprep).
// Last root arriver resets counters then broadcasts ph to all 8 gen words —
// only ~32 pollers per gen line, 8 lines in parallel.
__device__ __forceinline__ void gbar(unsigned* bar, unsigned ph){
  asm volatile("s_waitcnt vmcnt(0)" ::: "memory");   // my data stores are at L3
  __syncthreads();
  if (threadIdx.x == 0){
    const int g = (int)(blockIdx.x >> 5);
    unsigned a = __hip_atomic_fetch_add(bar + g * 64, 1u, __ATOMIC_RELAXED, __HIP_MEMORY_SCOPE_AGENT);
    bool done = false;
    if (a == 31u){
      unsigned r = __hip_atomic_fetch_add(bar + 512, 1u, __ATOMIC_RELAXED, __HIP_MEMORY_SCOPE_AGENT);
      if (r == 7u){
        __hip_atomic_store(bar + 512, 0u, __ATOMIC_RELAXED, __HIP_MEMORY_SCOPE_AGENT);
        #pragma unroll
        for (int i = 0; i < 8; ++i)
          __hip_atomic_store(bar + i * 64, 0u, __ATOMIC_RELAXED, __HIP_MEMORY_SCOPE_AGENT);
        asm volatile("s_waitcnt vmcnt(0)" ::: "memory"); // resets visible before gen flip
        #pragma unroll
        for (int i = 0; i < 8; ++i)
          __hip_atomic_store(bar + (16 + i) * 64, ph, __ATOMIC_RELAXED, __HIP_MEMORY_SCOPE_AGENT);
        done = true;
      }
    }
    if (!done){
      while (__hip_atomic_load(bar + (16 + g) * 64, __ATOMIC_RELAXED, __HIP_MEMORY_SCOPE_AGENT) != ph)
        __builtin_amdgcn_s_sleep(2);
    }
  }
  __syncthreads();
}

// ------------------------------------------------------------------
// prep: build embt, W0c/W1c (+combined biases), W1b; zero rowsum; zero bar.
__global__ __launch_bounds__(256) void kprep(Ptrs P){
  const int stride = gridDim.x * blockDim.x;
  const int i0 = blockIdx.x * blockDim.x + threadIdx.x;
  for (int i = i0; i < 2048; i += stride) P.bar[i] = 0u;
  // embt[t][b][k]
  for (int i = i0; i < T_ * B_ * 512; i += stride){
    int k = i & 511, tb = i >> 9, b = tb & 31, t = tb >> 5;
    int tok = (t == 0) ? 1 : P.padded[b * TO_ + (t - 1)];
    P.embt[i] = f2b(P.emb[(size_t)tok * 512 + k]);
  }
  // W0c[g'][k], g'=j*4+q, k<1024: Wih0[q*512+j][k], else Whh0[q*512+j][k-1024]
  for (int i = i0; i < 2048 * 1536; i += stride){
    int k = i % 1536, gp = i / 1536;
    int j = gp >> 2, q = gp & 3, g = q * 512 + j;
    float v = (k < 1024) ? P.Wih0[(size_t)g * 1024 + k] : P.Whh0[(size_t)g * 512 + (k - 1024)];
    P.W0c[i] = f2b(v);
  }
  for (int i = i0; i < 2048 * 1024; i += stride){
    int k = i & 1023, gp = i >> 10;
    int j = gp >> 2, q = gp & 3, g = q * 512 + j;
    float v = (k < 512) ? P.Wih1[(size_t)g * 512 + k] : P.Whh1[(size_t)g * 512 + (k - 512)];
    P.W1c[i] = f2b(v);
  }
  for (int i = i0; i < 2048; i += stride){
    int j = i >> 2, q = i & 3, g = q * 512 + j;
    P.bias0c[i] = P.bih0[g] + P.bhh0[g];
    P.bias1c[i] = P.bih1[g] + P.bhh1[g];
  }
  for (int i = i0; i < 512 * 1024; i += stride) P.W1b[i] = f2b(P.W1[i]);
  for (int i = i0; i < NROW_; i += stride) P.rowsum[i] = 0.f;
}

// kprep2 (after kA): W2 -> bf16, overlaying the dead W0c/W1c region
__global__ __launch_bounds__(256) void kprep2(Ptrs P){
  const int stride = gridDim.x * blockDim.x;
  const int i0 = blockIdx.x * blockDim.x + threadIdx.x;
  for (int i = i0; i < V_ * 512; i += stride) P.W2b[i] = f2b(P.W2[i]);
}

// ------------------------------------------------------------------
// Phase A: persistent cooperative recurrence, tree barrier, MFMA LSTM gates.
// Roles per phase:
//   S1: bb<128 GEMM layer0 (n-tile of 16 gates) ; bb in [128,160): mlpin att_c(t-1)
//   S2: bb<128 GEMM layer1 ; bb in [160,224): clear u[pp] ; bb==224: clear Zb[pp]
//   S34: all 256 blocks: attention (b_att=bb>>3, ti-chunk=(bb&7)*128)
__global__ __launch_bounds__(256, 1) void kA(Ptrs P){
  __shared__ __align__(16) unsigned short enc_s[128 * 512]; // 128 KB, XOR-swizzled
  __shared__ float h1_s[512];
  __shared__ float w_s[128];
  __shared__ float gate_s[32][17];
  __shared__ float h_s[32][4];
  const int bb = blockIdx.x, tid = threadIdx.x;
  const int b_att = bb >> 3;
  unsigned ph = 0;

  { // stage encoder slice -> LDS bf16 with byte^=((row&7)<<4) swizzle
    const float* ep = P.enc + ((size_t)b_att * TI_ + (size_t)(bb & 7) * 128) * H_;
    for (int idx = tid; idx < 128 * 512; idx += 256){
      int r = idx >> 9;
      unsigned byteoff = ((unsigned)idx * 2u) ^ ((unsigned)(r & 7) << 4);
      enc_s[byteoff >> 1] = f2b(ep[idx]);
    }
  }
  { // init state via agent atomics
    int g = bb * 256 + tid;                    // 0..65535
    if (g < 32768){ astf(P.u + g, 0.f); astf(P.Xh1f + g, 0.f); }
    if (g < 16384){ astw((unsigned*)P.Xh0 + g, 0u); astw((unsigned*)P.Xh1 + g, 0u); }
    if (g < 64) astf(P.Zb + g, (g >= 32) ? 1.f : 0.f);
  }
  gbar(P.bar, ++ph);

  const int wv = tid >> 6;              // wave id
  const int l  = tid & 63, lr = l & 15, lk = l >> 4;
  const int eidx = tid - 128;           // epilogue index (tid>=128)
  const int eb = eidx >> 2, ejl = eidx & 3;
  float c0r = 0.f, c1r = 0.f;           // cell state (threads 128..255)

  for (int t = 0; t < T_; ++t){
    const int p = t & 1, pp = p ^ 1;
    // ================= S1: LSTM layer 0 =================
    if (bb < 128){
      if (wv < 2){
        const int batch = wv * 16 + lr;
        const unsigned short* Brow = P.W0c + (size_t)(bb * 16 + lr) * 1536;
        const unsigned short* Erow = P.embt + ((size_t)t * 32 + batch) * 512;
        const float* Urow = P.u + pp * 16384 + batch * 512;
        const unsigned long long* Hrow =
            (const unsigned long long*)(P.Xh0 + pp * 16384 + batch * 512);
        const float rZ = 1.f / aldf(P.Zb + pp * 32 + batch);
        f32x4 acc = {0.f, 0.f, 0.f, 0.f};
        #pragma unroll
        for (int ks = 0; ks < 16; ++ks){            // e-segment (plain, L2)
          s16x8 a = *(const s16x8*)(Erow + ks * 32 + lk * 8);
          s16x8 b = *(const s16x8*)(Brow + ks * 32 + lk * 8);
          acc = __builtin_amdgcn_mfma_f32_16x16x32_bf16(a, b, acc, 0, 0, 0);
        }
        #pragma unroll
        for (int ks = 0; ks < 16; ++ks){            // att_c segment (u * rZ)
          const int kb = ks * 32 + lk * 8;
          unsigned long long dd[4];
          dd[0] = aldu((const unsigned long long*)(Urow + kb));
          dd[1] = aldu((const unsigned long long*)(Urow + kb + 2));
          dd[2] = aldu((const unsigned long long*)(Urow + kb + 4));
          dd[3] = aldu((const unsigned long long*)(Urow + kb + 6));
          float uf[8]; __builtin_memcpy(uf, dd, 32);
          s16x8 a;
          #pragma unroll
          for (int e = 0; e < 8; ++e) a[e] = (short)f2b(uf[e] * rZ);
          s16x8 b = *(const s16x8*)(Brow + 512 + kb);
          acc = __builtin_amdgcn_mfma_f32_16x16x32_bf16(a, b, acc, 0, 0, 0);
        }
        #pragma unroll
        for (int ks = 0; ks < 16; ++ks){            // h0_prev segment (bf16)
          const int kb = ks * 32 + lk * 8;
          unsigned long long dd[2];
          dd[0] = aldu(Hrow + (kb >> 2));
          dd[1] = aldu(Hrow + (kb >> 2) + 1);
          s16x8 a; __builtin_memcpy(&a, dd, 16);
          s16x8 b = *(const s16x8*)(Brow + 1024 + kb);
          acc = __builtin_amdgcn_mfma_f32_16x16x32_bf16(a, b, acc, 0, 0, 0);
        }
        #pragma unroll
        for (int j = 0; j < 4; ++j) gate_s[wv * 16 + lk * 4 + j][lr] = acc[j];
      }
    } else if (bb < 160 && t > 0){
      // write mlpin att_c(t-1) for batch b = bb-128
      const int b = bb - 128;
      const float rZ = 1.f / aldf(P.Zb + pp * 32 + b);
      unsigned long long v = aldu((const unsigned long long*)(P.u + pp * 16384 + b * 512) + tid);
      float f2[2]; __builtin_memcpy(f2, &v, 8);
      unsigned pk = (unsigned)f2b(f2[0] * rZ) | ((unsigned)f2b(f2[1] * rZ) << 16);
      *(unsigned*)(P.mlpin + ((size_t)(t - 1) * 32 + b) * 1024 + 512 + tid * 2) = pk;
    }
    __syncthreads();
    if (bb < 128 && tid >= 128){
      const float* bs = P.bias0c + bb * 16 + ejl * 4;
      float ii = sigf (gate_s[eb][ejl * 4 + 0] + bs[0]);
      float ff = sigf (gate_s[eb][ejl * 4 + 1] + bs[1]);
      float gg = tanhf(gate_s[eb][ejl * 4 + 2] + bs[2]);
      float oo = sigf (gate_s[eb][ejl * 4 + 3] + bs[3]);
      float cn = ff * c0r + ii * gg; c0r = cn;
      h_s[eb][ejl] = oo * tanhf(cn);
    }
    __syncthreads();
    if (bb < 128 && tid < 32){
      unsigned short hb[4];
      #pragma unroll
      for (int jl = 0; jl < 4; ++jl) hb[jl] = f2b(h_s[tid][jl]);
      unsigned long long v; __builtin_memcpy(&v, hb, 8);
      astu((unsigned long long*)(P.Xh0 + p * 16384 + tid * 512 + bb * 4), v);
    }
    gbar(P.bar, ++ph);
    // ================= S2: LSTM layer 1 =================
    if (bb < 128){
      if (wv < 2){
        const int batch = wv * 16 + lr;
        const unsigned short* Brow = P.W1c + (size_t)(bb * 16 + lr) * 1024;
        const unsigned long long* H0r =
            (const unsigned long long*)(P.Xh0 + p * 16384 + batch * 512);
        const unsigned long long* H1r =
            (const unsigned long long*)(P.Xh1 + pp * 16384 + batch * 512);
        f32x4 acc = {0.f, 0.f, 0.f, 0.f};
        #pragma unroll
        for (int ks = 0; ks < 16; ++ks){            // h0(t) segment
          const int kb = ks * 32 + lk * 8;
          unsigned long long dd[2];
          dd[0] = aldu(H0r + (kb >> 2));
          dd[1] = aldu(H0r + (kb >> 2) + 1);
          s16x8 a; __builtin_memcpy(&a, dd, 16);
          s16x8 b = *(const s16x8*)(Brow + kb);
          acc = __builtin_amdgcn_mfma_f32_16x16x32_bf16(a, b, acc, 0, 0, 0);
        }
        #pragma unroll
        for (int ks = 0; ks < 16; ++ks){            // h1(t-1) segment
          const int kb = ks * 32 + lk * 8;
          unsigned long long dd[2];
          dd[0] = aldu(H1r + (kb >> 2));
          dd[1] = aldu(H1r + (kb >> 2) + 1);
          s16x8 a; __builtin_memcpy(&a, dd, 16);
          s16x8 b = *(const s16x8*)(Brow + 512 + kb);
          acc = __builtin_amdgcn_mfma_f32_16x16x32_bf16(a, b, acc, 0, 0, 0);
        }
        #pragma unroll
        for (int j = 0; j < 4; ++j) gate_s[wv * 16 + lk * 4 + j][lr] = acc[j];
      }
    } else if (bb < 224){
      astf(P.u + pp * 16384 + (bb - 160) * 256 + tid, 0.f);  // clear u[pp]
    } else if (bb == 224 && tid < 32){
      astf(P.Zb + pp * 32 + tid, 0.f);
    }
    __syncthreads();
    if (bb < 128 && tid >= 128){
      const float* bs = P.bias1c + bb * 16 + ejl * 4;
      float ii = sigf (gate_s[eb][ejl * 4 + 0] + bs[0]);
      float ff = sigf (gate_s[eb][ejl * 4 + 1] + bs[1]);
      float gg = tanhf(gate_s[eb][ejl * 4 + 2] + bs[2]);
      float oo = sigf (gate_s[eb][ejl * 4 + 3] + bs[3]);
      float cn = ff * c1r + ii * gg; c1r = cn;
      h_s[eb][ejl] = oo * tanhf(cn);
    }
    __syncthreads();
    if (bb < 128 && tid < 32){
      unsigned short hb[4];
      #pragma unroll
      for (int jl = 0; jl < 4; ++jl) hb[jl] = f2b(h_s[tid][jl]);
      unsigned long long vb; __builtin_memcpy(&vb, hb, 8);
      astu((unsigned long long*)(P.Xh1 + p * 16384 + tid * 512 + bb * 4), vb);
      *(unsigned long long*)(P.mlpin + ((size_t)t * 32 + tid) * 1024 + bb * 4) = vb;
      unsigned long long w0, w1;
      __builtin_memcpy(&w0, &h_s[tid][0], 8);
      __builtin_memcpy(&w1, &h_s[tid][2], 8);
      unsigned long long* dst = (unsigned long long*)P.Xh1f + ((p * 16384 + tid * 512 + bb * 4) >> 1);
      astu(dst, w0); astu(dst + 1, w1);
    }
    gbar(P.bar, ++ph);
    // ================= S34: attention (scores+softmax+context) =================
    {
      unsigned long long v = aldu((const unsigned long long*)(P.Xh1f + p * 16384 + b_att * 512) + tid);
      float f2[2]; __builtin_memcpy(f2, &v, 8);
      h1_s[tid * 2] = f2[0]; h1_s[tid * 2 + 1] = f2[1];
    }
    __syncthreads();
    {
      const int ti_l = tid >> 1, half = tid & 1;
      float s = 0.f;
      const unsigned swz = (unsigned)(ti_l & 7) << 4;
      for (int h8 = half * 256; h8 < half * 256 + 256; h8 += 8){
        unsigned byteoff = ((unsigned)(ti_l * 512 + h8) * 2u) ^ swz;
        s16x8 ev = *(const s16x8*)((const char*)enc_s + byteoff);
        #pragma unroll
        for (int e = 0; e < 8; ++e) s += b2f((unsigned short)ev[e]) * h1_s[h8 + e];
      }
      s += __shfl_xor(s, 1);
      if (half == 0) w_s[ti_l] = expf(s);       // no max-shift: |s| << 88
    }
    __syncthreads();
    {
      if (tid < 128){
        float z = w_s[tid];
        #pragma unroll
        for (int off = 1; off < 64; off <<= 1) z += __shfl_xor(z, off);
        if ((tid & 63) == 0) unsafeAtomicAdd(P.Zb + p * 32 + b_att, z);
      }
      // context: each thread owns h-pair (2 bf16 = one b32 LDS read per ti)
      float a0 = 0.f, a1 = 0.f;
      const int hc = tid * 2;
      for (int ti = 0; ti < 128; ++ti){
        const float wvv = w_s[ti];
        unsigned byteoff = ((unsigned)(ti * 1024 + hc * 2)) ^ ((unsigned)(ti & 7) << 4);
        unsigned pk = *(const unsigned*)((const char*)enc_s + byteoff);
        a0 += wvv * b2f((unsigned short)(pk & 0xffffu));
        a1 += wvv * b2f((unsigned short)(pk >> 16));
      }
      unsafeAtomicAdd(P.u + p * 16384 + b_att * 512 + hc, a0);
      unsafeAtomicAdd(P.u + p * 16384 + b_att * 512 + hc + 1, a1);
    }
    gbar(P.bar, ++ph);
  }
  // final att_c (t=256, p=0)
  if (bb >= 128 && bb < 160){
    const int b = bb - 128;
    const float rZ = 1.f / aldf(P.Zb + 0 * 32 + b);
    unsigned long long v = aldu((const unsigned long long*)(P.u + 0 * 16384 + b * 512) + tid);
    float f2[2]; __builtin_memcpy(f2, &v, 8);
    unsigned pk = (unsigned)f2b(f2[0] * rZ) | ((unsigned)f2b(f2[1] * rZ) << 16);
    *(unsigned*)(P.mlpin + ((size_t)256 * 32 + b) * 1024 + 512 + tid * 2) = pk;
  }
}

// ------------------------------------------------------------------
// B1: tanhv = tanh(mlpin @ W1^T + b1)   M=8224 N=512 K=1024, bf16 MFMA
__global__ __launch_bounds__(256) void kB1(Ptrs P){
  const int wid = blockIdx.x * 4 + (threadIdx.x >> 6);
  if (wid >= 129 * 8) return;
  const int mt = wid >> 3, nt = wid & 7;
  const int l = threadIdx.x & 63, lr = l & 15, lk = l >> 4;
  const int mr = mt * 64, nc = nt * 64;
  f32x4 acc[4][4] = {};
  for (int k0 = 0; k0 < 1024; k0 += 32){
    s16x8 af[4], bfm[4];
    #pragma unroll
    for (int f = 0; f < 4; ++f){
      int row = mr + f * 16 + lr; if (row > NROW_ - 1) row = NROW_ - 1;
      af[f] = *(const s16x8*)(P.mlpin + (size_t)row * 1024 + k0 + lk * 8);
      int col = nc + f * 16 + lr;
      bfm[f] = *(const s16x8*)(P.W1b + (size_t)col * 1024 + k0 + lk * 8);
    }
    #pragma unroll
    for (int fi = 0; fi < 4; ++fi)
      #pragma unroll
      for (int fj = 0; fj < 4; ++fj)
        acc[fi][fj] = __builtin_amdgcn_mfma_f32_16x16x32_bf16(af[fi], bfm[fj], acc[fi][fj], 0, 0, 0);
  }
  #pragma unroll
  for (int fi = 0; fi < 4; ++fi){
    #pragma unroll
    for (int jj = 0; jj < 4; ++jj){
      int m = mr + fi * 16 + lk * 4 + jj;
      if (m >= NROW_) continue;
      #pragma unroll
      for (int fj = 0; fj < 4; ++fj){
        int n = nc + fj * 16 + lr;
        P.tanhv[(size_t)m * 512 + n] = f2b(tanhf(acc[fi][fj][jj] + P.b1[n]));
      }
    }
  }
}

// B2: logits = tanhv @ W2^T + b2, fused exp-rowsum.  M=8224 N=10000 K=512
__global__ __launch_bounds__(256) void kB2(Ptrs P){
  const int wid = blockIdx.x * 4 + (threadIdx.x >> 6);
  if (wid >= 129 * 157) return;
  const int mt = wid / 157, nt = wid % 157;
  const int l = threadIdx.x & 63, lr = l & 15, lk = l >> 4;
  const int mr = mt * 64, nc = nt * 64;
  f32x4 acc[4][4] = {};
  for (int k0 = 0; k0 < 512; k0 += 32){
    s16x8 af[4], bfm[4];
    #pragma unroll
    for (int f = 0; f < 4; ++f){
      int row = mr + f * 16 + lr; if (row > NROW_ - 1) row = NROW_ - 1;
      af[f] = *(const s16x8*)(P.tanhv + (size_t)row * 512 + k0 + lk * 8);
      int col = nc + f * 16 + lr; if (col > V_ - 1) col = V_ - 1;
      bfm[f] = *(const s16x8*)(P.W2b + (size_t)col * 512 + k0 + lk * 8);
    }
    #pragma unroll
    for (int fi = 0; fi < 4; ++fi)
      #pragma unroll
      for (int fj = 0; fj < 4; ++fj)
        acc[fi][fj] = __builtin_amdgcn_mfma_f32_16x16x32_bf16(af[fi], bfm[fj], acc[fi][fj], 0, 0, 0);
  }
  #pragma unroll
  for (int fi = 0; fi < 4; ++fi){
    #pragma unroll
    for (int jj = 0; jj < 4; ++jj){
      const int m = mr + fi * 16 + lk * 4 + jj;
      float s = 0.f;
      #pragma unroll
      for (int fj = 0; fj < 4; ++fj){
        int n = nc + fj * 16 + lr;
        if (n < V_) s += expf(acc[fi][fj][jj] + P.b2[n]);
      }
      s += __shfl_xor(s, 1); s += __shfl_xor(s, 2);
      s += __shfl_xor(s, 4); s += __shfl_xor(s, 8);
      if (lr == 0 && m < NROW_) unsafeAtomicAdd(P.rowsum + m, s);
    }
  }
}

// label logit per row (one wave per row)
__global__ __launch_bounds__(256) void kL1(Ptrs P){
  const int wid = blockIdx.x * 4 + (threadIdx.x >> 6);
  if (wid >= NROW_) return;
  const int l = threadIdx.x & 63;
  const int t = wid >> 5, b = wid & 31;
  const int lab = (t < TO_) ? P.padded[b * TO_ + t] : 2;   // EOS=2
  float s = 0.f;
  s16x8 av = *(const s16x8*)(P.tanhv + (size_t)wid * 512 + l * 8);
  s16x8 wv = *(const s16x8*)(P.W2b + (size_t)lab * 512 + l * 8);
  #pragma unroll
  for (int e = 0; e < 8; ++e) s += b2f((unsigned short)av[e]) * b2f((unsigned short)wv[e]);
  #pragma unroll
  for (int off = 1; off < 64; off <<= 1) s += __shfl_xor(s, off);
  if (l == 0) P.lablog[wid] = s + P.b2[lab];
}

// final masked-NLL reduction
__global__ __launch_bounds__(512) void kL2(Ptrs P){
  __shared__ float ssum[8], scnt[8];
  const int tid = threadIdx.x;
  float sum = 0.f, cnt = 0.f;
  for (int r = tid; r < NROW_; r += 512){
    int t = r >> 5, b = r & 31;
    int lab = (t < TO_) ? P.padded[b * TO_ + t] : 2;
    if (lab != 0){ sum += logf(P.rowsum[r]) - P.lablog[r]; cnt += 1.f; }
  }
  #pragma unroll
  for (int off = 1; off < 64; off <<= 1){ sum += __shfl_xor(sum, off); cnt += __shfl_xor(cnt, off); }
  if ((tid & 63) == 0){ ssum[tid >> 6] = sum; scnt[tid >> 6] = cnt; }
  __syncthreads();
  if (tid == 0){
    float S = 0.f, C = 0.f;
    for (int i = 0; i < 8; ++i){ S += ssum[i]; C += scnt[i]; }
    P.out[0] = S / fmaxf(C, 1.f);
  }
}

// ------------------------------------------------------------------
extern "C" void kernel_launch(void* const* d_in, const int* in_sizes, int n_in,
                              void* d_out, int out_size, void* d_ws, size_t ws_size,
                              hipStream_t stream){
  (void)in_sizes; (void)n_in; (void)out_size; (void)ws_size;
  Ptrs P;
  P.padded = (const int*)d_in[0];
  P.enc    = (const float*)d_in[1];
  P.emb    = (const float*)d_in[2];
  P.Wih0 = (const float*)d_in[3];  P.Whh0 = (const float*)d_in[4];
  P.bih0 = (const float*)d_in[5];  P.bhh0 = (const float*)d_in[6];
  P.Wih1 = (const float*)d_in[7];  P.Whh1 = (const float*)d_in[8];
  P.bih1 = (const float*)d_in[9];  P.bhh1 = (const float*)d_in[10];
  P.W1 = (const float*)d_in[11];   P.b1 = (const float*)d_in[12];
  P.W2 = (const float*)d_in[13];   P.b2 = (const float*)d_in[14];
  P.out = (float*)d_out;

  char* w = (char*)d_ws;
  size_t off = 0;
  auto take = [&](size_t bytes) -> void* {
    void* ptr = (void*)(w + off);
    off += (bytes + 255) & ~(size_t)255;
    return ptr;
  };
  P.mlpin  = (unsigned short*)take((size_t)T_ * B_ * 1024 * 2);   // 16.84 MB
  P.embt   = (unsigned short*)take((size_t)T_ * B_ * 512 * 2);    // 8.42 MB
  P.tanhv  = P.embt;                                              // overlay (post-kA)
  P.W0c    = (unsigned short*)take((size_t)2048 * 1536 * 2);      // 6.29 MB
  P.W1c    = (unsigned short*)take((size_t)2048 * 1024 * 2);      // 4.19 MB
  P.W2b    = P.W0c;                                               // overlay (post-kA)
  P.W1b    = (unsigned short*)take((size_t)512 * 1024 * 2);       // 1.05 MB
  P.bias0c = (float*)take(2048 * 4);
  P.bias1c = (float*)take(2048 * 4);
  P.u      = (float*)take(2 * 32 * 512 * 4);
  P.Xh0    = (unsigned short*)take(2 * 32 * 512 * 2);
  P.Xh1    = (unsigned short*)take(2 * 32 * 512 * 2);
  P.Xh1f   = (float*)take(2 * 32 * 512 * 4);
  P.Zb     = (float*)take(2 * 32 * 4);
  P.bar    = (unsigned*)take(8192);
  P.rowsum = (float*)take(NROW_ * 4);
  P.lablog = (float*)take(NROW_ * 4);

  kprep<<<dim3(2048), dim3(256), 0, stream>>>(P);
  void* args[] = { (void*)&P };
  hipLaunchCooperativeKernel(kA, dim3(NB_), dim3(256), args, 0, stream);
  kprep2<<<dim3(1024), dim3(256), 0, stream>>>(P);
  kB1<<<dim3(258),  dim3(256), 0, stream>>>(P);
  kB2<<<dim3(5064), dim3(256), 0, stream>>>(P);
  kL1<<<dim3(2056), dim3(256), 0, stream>>>(P);
  kL2<<<dim3(1),    dim3(512), 0, stream>>>(P);
}

// Round 4
// 9451.419 us; speedup vs baseline: 6.2349x; 1.0040x over previous
//
#include <hip/hip_runtime.h>
#include <hip/hip_bf16.h>

// Problem constants
#define B_    32
#define TO_   256
#define T_    257        // To+1 decode steps
#define H_    512
#define V_    10000
#define TI_   1024
#define NROW_ 8224       // T_*B_
#define NB_   256        // blocks in cooperative kernel

using f32x4 = __attribute__((ext_vector_type(4))) float;
using s16x8 = __attribute__((ext_vector_type(8))) short;

struct Ptrs {
  const int* padded;
  const float* enc;
  const float* emb;
  const float *Wih0, *Whh0, *bih0, *bhh0;
  const float *Wih1, *Whh1, *bih1, *bhh1;
  const float *W1, *b1, *W2, *b2;
  float* out;
  // workspace
  unsigned short *mlpin;   // [257][32][1024] bf16  (=[h1 | att_c])
  unsigned short *embt;    // [257][32][512] bf16 embedded tokens; tanhv overlays after kA
  unsigned short *tanhv;   // [8224][512] bf16 (== embt region)
  unsigned short *W0c;     // [2048][1536] bf16, row g'=j*4+q = [Wih0row | Whh0row]; W2b overlays
  unsigned short *W1c;     // [2048][1024] bf16, row g'=j*4+q = [Wih1row | Whh1row]
  unsigned short *W1b;     // [512][1024] bf16
  unsigned short *W2b;     // [10000][512] bf16 (== W0c region, filled by kprep2)
  float *bias0c, *bias1c;  // [2048] combined biases, gate-interleaved
  float *u;                // [2][32][512] unnormalized context (atomicAdd)
  unsigned short *Xh0;     // [2][32][512] bf16 h0 state
  unsigned short *Xh1;     // [2][32][512] bf16 h1 state
  float *Xh1f;             // [2][32][512] f32 h1 state (attention)
  float *Zb;               // [2][32] softmax denominators
  unsigned *bar;           // flag-array barrier region (4 KB used)
  float *rowsum;           // [8224]
  float *lablog;           // [8224]
};

__device__ __forceinline__ unsigned short f2b(float f){
  __hip_bfloat16 h = __float2bfloat16(f);
  unsigned short r; __builtin_memcpy(&r, &h, 2); return r;
}
__device__ __forceinline__ float b2f(unsigned short u){
  unsigned v = ((unsigned)u) << 16; float f; __builtin_memcpy(&f, &v, 4); return f;
}
__device__ __forceinline__ float sigf(float x){ return 1.f / (1.f + expf(-x)); }

// ---- agent-scope (device) relaxed atomics: bypass non-coherent L1/L2 ----
__device__ __forceinline__ float aldf(const float* p){
  return __hip_atomic_load(p, __ATOMIC_RELAXED, __HIP_MEMORY_SCOPE_AGENT);
}
__device__ __forceinline__ unsigned aldw(const unsigned* p){
  return __hip_atomic_load(p, __ATOMIC_RELAXED, __HIP_MEMORY_SCOPE_AGENT);
}
__device__ __forceinline__ unsigned long long aldu(const unsigned long long* p){
  return __hip_atomic_load(p, __ATOMIC_RELAXED, __HIP_MEMORY_SCOPE_AGENT);
}
__device__ __forceinline__ void astf(float* p, float v){
  __hip_atomic_store(p, v, __ATOMIC_RELAXED, __HIP_MEMORY_SCOPE_AGENT);
}
__device__ __forceinline__ void astu(unsigned long long* p, unsigned long long v){
  __hip_atomic_store(p, v, __ATOMIC_RELAXED, __HIP_MEMORY_SCOPE_AGENT);
}
__device__ __forceinline__ void astw(unsigned* p, unsigned v){
  __hip_atomic_store(p, v, __ATOMIC_RELAXED, __HIP_MEMORY_SCOPE_AGENT);
}

// Flag-array grid barrier: NO atomic RMW anywhere.
// Block i's flag lives at bar[i*4] (16B apart). Arrive = plain relaxed store
// of monotonically-increasing phase id. Detect = wave 0 scans all flags
// (4 per lane) until all >= ph. Monotonic ph + ">=" makes reuse safe (max
// skew between blocks is 1 phase).
__device__ __forceinline__ void gbar(unsigned* bar, unsigned ph){
  asm volatile("s_waitcnt vmcnt(0)" ::: "memory");   // my data stores are at L3
  __syncthreads();
  if (threadIdx.x < 64){
    const int l = threadIdx.x;
    if (l == 0) astw(bar + blockIdx.x * 4, ph);
    for (;;){
      unsigned f0 = aldw(bar + (l      ) * 4);
      unsigned f1 = aldw(bar + (l +  64) * 4);
      unsigned f2 = aldw(bar + (l + 128) * 4);
      unsigned f3 = aldw(bar + (l + 192) * 4);
      bool ok = (f0 >= ph) & (f1 >= ph) & (f2 >= ph) & (f3 >= ph);
      if (__all(ok)) break;
      __builtin_amdgcn_s_sleep(2);
    }
  }
  __syncthreads();
}

// 128-participant variant: only blocks 0..127 arrive & scan flags 0..127.
__device__ __forceinline__ void gbar128(unsigned* bar, unsigned ph){
  asm volatile("s_waitcnt vmcnt(0)" ::: "memory");
  __syncthreads();
  if (threadIdx.x < 64){
    const int l = threadIdx.x;
    if (l == 0) astw(bar + blockIdx.x * 4, ph);
    for (;;){
      unsigned f0 = aldw(bar + (l     ) * 4);
      unsigned f1 = aldw(bar + (l + 64) * 4);
      bool ok = (f0 >= ph) & (f1 >= ph);
      if (__all(ok)) break;
      __builtin_amdgcn_s_sleep(2);
    }
  }
  __syncthreads();
}

// ------------------------------------------------------------------
// prep: build embt, W0c/W1c (+combined biases), W1b; zero rowsum; zero bar.
__global__ __launch_bounds__(256) void kprep(Ptrs P){
  const int stride = gridDim.x * blockDim.x;
  const int i0 = blockIdx.x * blockDim.x + threadIdx.x;
  for (int i = i0; i < 2048; i += stride) P.bar[i] = 0u;
  // embt[t][b][k]
  for (int i = i0; i < T_ * B_ * 512; i += stride){
    int k = i & 511, tb = i >> 9, b = tb & 31, t = tb >> 5;
    int tok = (t == 0) ? 1 : P.padded[b * TO_ + (t - 1)];
    P.embt[i] = f2b(P.emb[(size_t)tok * 512 + k]);
  }
  // W0c[g'][k], g'=j*4+q, k<1024: Wih0[q*512+j][k], else Whh0[q*512+j][k-1024]
  for (int i = i0; i < 2048 * 1536; i += stride){
    int k = i % 1536, gp = i / 1536;
    int j = gp >> 2, q = gp & 3, g = q * 512 + j;
    float v = (k < 1024) ? P.Wih0[(size_t)g * 1024 + k] : P.Whh0[(size_t)g * 512 + (k - 1024)];
    P.W0c[i] = f2b(v);
  }
  for (int i = i0; i < 2048 * 1024; i += stride){
    int k = i & 1023, gp = i >> 10;
    int j = gp >> 2, q = gp & 3, g = q * 512 + j;
    float v = (k < 512) ? P.Wih1[(size_t)g * 512 + k] : P.Whh1[(size_t)g * 512 + (k - 512)];
    P.W1c[i] = f2b(v);
  }
  for (int i = i0; i < 2048; i += stride){
    int j = i >> 2, q = i & 3, g = q * 512 + j;
    P.bias0c[i] = P.bih0[g] + P.bhh0[g];
    P.bias1c[i] = P.bih1[g] + P.bhh1[g];
  }
  for (int i = i0; i < 512 * 1024; i += stride) P.W1b[i] = f2b(P.W1[i]);
  for (int i = i0; i < NROW_; i += stride) P.rowsum[i] = 0.f;
}

// kprep2 (after kA): W2 -> bf16, overlaying the dead W0c/W1c region
__global__ __launch_bounds__(256) void kprep2(Ptrs P){
  const int stride = gridDim.x * blockDim.x;
  const int i0 = blockIdx.x * blockDim.x + threadIdx.x;
  for (int i = i0; i < V_ * 512; i += stride) P.W2b[i] = f2b(P.W2[i]);
}

// ------------------------------------------------------------------
// Phase A: persistent cooperative recurrence, flag barrier, MFMA LSTM gates.
// Phases per step (ph base = 3t):
//   S1 [barX=3t+2, 128-blk]: bb<128 GEMM layer0 ; 128-159: mlpin att_c(t-1) ;
//                            160-223: clear u[p] ; 224: clear Zb[p]
//   S2 [barY=3t+3, all]:     bb<128 GEMM layer1 (others idle)
//   S34[barZ=3t+4, all]:     all blocks: attention (b_att=bb>>3, chunk=(bb&7)*128)
__global__ __launch_bounds__(256, 1) void kA(Ptrs P){
  __shared__ __align__(16) unsigned short enc_s[128 * 512]; // 128 KB, XOR-swizzled
  __shared__ float h1_s[512];
  __shared__ float w_s[128];
  __shared__ float gate_s[32][17];
  __shared__ float h_s[32][4];
  const int bb = blockIdx.x, tid = threadIdx.x;
  const int b_att = bb >> 3;

  { // stage encoder slice -> LDS bf16 with byte^=((row&7)<<4) swizzle
    const float* ep = P.enc + ((size_t)b_att * TI_ + (size_t)(bb & 7) * 128) * H_;
    for (int idx = tid; idx < 128 * 512; idx += 256){
      int r = idx >> 9;
      unsigned byteoff = ((unsigned)idx * 2u) ^ ((unsigned)(r & 7) << 4);
      enc_s[byteoff >> 1] = f2b(ep[idx]);
    }
  }
  { // init state via agent atomics
    int g = bb * 256 + tid;                    // 0..65535
    if (g < 32768){ astf(P.u + g, 0.f); astf(P.Xh1f + g, 0.f); }
    if (g < 16384){ astw((unsigned*)P.Xh0 + g, 0u); astw((unsigned*)P.Xh1 + g, 0u); }
    if (g < 64) astf(P.Zb + g, (g >= 32) ? 1.f : 0.f);
  }
  gbar(P.bar, 1u);

  const int wv = tid >> 6;              // wave id
  const int l  = tid & 63, lr = l & 15, lk = l >> 4;
  const int eidx = tid - 128;           // epilogue index (tid>=128)
  const int eb = eidx >> 2, ejl = eidx & 3;
  float c0r = 0.f, c1r = 0.f;           // cell state (threads 128..255)

  for (int t = 0; t < T_; ++t){
    const int p = t & 1, pp = p ^ 1;
    const unsigned phb = 3u * (unsigned)t;
    // ================= S1: LSTM layer 0 =================
    if (bb < 128){
      if (wv < 2){
        const int batch = wv * 16 + lr;
        const unsigned short* Brow = P.W0c + (size_t)(bb * 16 + lr) * 1536;
        const unsigned short* Erow = P.embt + ((size_t)t * 32 + batch) * 512;
        const float* Urow = P.u + pp * 16384 + batch * 512;
        const unsigned long long* Hrow =
            (const unsigned long long*)(P.Xh0 + pp * 16384 + batch * 512);
        const float rZ = 1.f / aldf(P.Zb + pp * 32 + batch);
        f32x4 acc = {0.f, 0.f, 0.f, 0.f};
        #pragma unroll
        for (int ks = 0; ks < 16; ++ks){            // e-segment (plain, L2)
          s16x8 a = *(const s16x8*)(Erow + ks * 32 + lk * 8);
          s16x8 b = *(const s16x8*)(Brow + ks * 32 + lk * 8);
          acc = __builtin_amdgcn_mfma_f32_16x16x32_bf16(a, b, acc, 0, 0, 0);
        }
        #pragma unroll
        for (int ks = 0; ks < 16; ++ks){            // att_c segment (u * rZ)
          const int kb = ks * 32 + lk * 8;
          unsigned long long dd[4];
          dd[0] = aldu((const unsigned long long*)(Urow + kb));
          dd[1] = aldu((const unsigned long long*)(Urow + kb + 2));
          dd[2] = aldu((const unsigned long long*)(Urow + kb + 4));
          dd[3] = aldu((const unsigned long long*)(Urow + kb + 6));
          float uf[8]; __builtin_memcpy(uf, dd, 32);
          s16x8 a;
          #pragma unroll
          for (int e = 0; e < 8; ++e) a[e] = (short)f2b(uf[e] * rZ);
          s16x8 b = *(const s16x8*)(Brow + 512 + kb);
          acc = __builtin_amdgcn_mfma_f32_16x16x32_bf16(a, b, acc, 0, 0, 0);
        }
        #pragma unroll
        for (int ks = 0; ks < 16; ++ks){            // h0_prev segment (bf16)
          const int kb = ks * 32 + lk * 8;
          unsigned long long dd[2];
          dd[0] = aldu(Hrow + (kb >> 2));
          dd[1] = aldu(Hrow + (kb >> 2) + 1);
          s16x8 a; __builtin_memcpy(&a, dd, 16);
          s16x8 b = *(const s16x8*)(Brow + 1024 + kb);
          acc = __builtin_amdgcn_mfma_f32_16x16x32_bf16(a, b, acc, 0, 0, 0);
        }
        #pragma unroll
        for (int j = 0; j < 4; ++j) gate_s[wv * 16 + lk * 4 + j][lr] = acc[j];
      }
    } else if (bb < 160){
      if (t > 0){
        // write mlpin att_c(t-1) for batch b = bb-128
        const int b = bb - 128;
        const float rZ = 1.f / aldf(P.Zb + pp * 32 + b);
        unsigned long long v = aldu((const unsigned long long*)(P.u + pp * 16384 + b * 512) + tid);
        float f2[2]; __builtin_memcpy(f2, &v, 8);
        unsigned pk = (unsigned)f2b(f2[0] * rZ) | ((unsigned)f2b(f2[1] * rZ) << 16);
        *(unsigned*)(P.mlpin + ((size_t)(t - 1) * 32 + b) * 1024 + 512 + tid * 2) = pk;
      }
    } else if (bb < 224){
      astf(P.u + p * 16384 + (bb - 160) * 256 + tid, 0.f);   // clear u[p] for S34(t)
    } else if (bb == 224 && tid < 32){
      astf(P.Zb + p * 32 + tid, 0.f);                        // clear Zb[p] for S34(t)
    }
    if (bb < 128){
      __syncthreads();
      if (tid >= 128){
        const float* bs = P.bias0c + bb * 16 + ejl * 4;
        float ii = sigf (gate_s[eb][ejl * 4 + 0] + bs[0]);
        float ff = sigf (gate_s[eb][ejl * 4 + 1] + bs[1]);
        float gg = tanhf(gate_s[eb][ejl * 4 + 2] + bs[2]);
        float oo = sigf (gate_s[eb][ejl * 4 + 3] + bs[3]);
        float cn = ff * c0r + ii * gg; c0r = cn;
        h_s[eb][ejl] = oo * tanhf(cn);
      }
      __syncthreads();
      if (tid < 32){
        unsigned short hb[4];
        #pragma unroll
        for (int jl = 0; jl < 4; ++jl) hb[jl] = f2b(h_s[tid][jl]);
        unsigned long long v; __builtin_memcpy(&v, hb, 8);
        astu((unsigned long long*)(P.Xh0 + p * 16384 + tid * 512 + bb * 4), v);
      }
      gbar128(P.bar, phb + 2u);   // S1->S2: only the 128 GEMM blocks rendezvous
    }
    // ================= S2: LSTM layer 1 =================
    if (bb < 128){
      if (wv < 2){
        const int batch = wv * 16 + lr;
        const unsigned short* Brow = P.W1c + (size_t)(bb * 16 + lr) * 1024;
        const unsigned long long* H0r =
            (const unsigned long long*)(P.Xh0 + p * 16384 + batch * 512);
        const unsigned long long* H1r =
            (const unsigned long long*)(P.Xh1 + pp * 16384 + batch * 512);
        f32x4 acc = {0.f, 0.f, 0.f, 0.f};
        #pragma unroll
        for (int ks = 0; ks < 16; ++ks){            // h0(t) segment
          const int kb = ks * 32 + lk * 8;
          unsigned long long dd[2];
          dd[0] = aldu(H0r + (kb >> 2));
          dd[1] = aldu(H0r + (kb >> 2) + 1);
          s16x8 a; __builtin_memcpy(&a, dd, 16);
          s16x8 b = *(const s16x8*)(Brow + kb);
          acc = __builtin_amdgcn_mfma_f32_16x16x32_bf16(a, b, acc, 0, 0, 0);
        }
        #pragma unroll
        for (int ks = 0; ks < 16; ++ks){            // h1(t-1) segment
          const int kb = ks * 32 + lk * 8;
          unsigned long long dd[2];
          dd[0] = aldu(H1r + (kb >> 2));
          dd[1] = aldu(H1r + (kb >> 2) + 1);
          s16x8 a; __builtin_memcpy(&a, dd, 16);
          s16x8 b = *(const s16x8*)(Brow + 512 + kb);
          acc = __builtin_amdgcn_mfma_f32_16x16x32_bf16(a, b, acc, 0, 0, 0);
        }
        #pragma unroll
        for (int j = 0; j < 4; ++j) gate_s[wv * 16 + lk * 4 + j][lr] = acc[j];
      }
      __syncthreads();
      if (tid >= 128){
        const float* bs = P.bias1c + bb * 16 + ejl * 4;
        float ii = sigf (gate_s[eb][ejl * 4 + 0] + bs[0]);
        float ff = sigf (gate_s[eb][ejl * 4 + 1] + bs[1]);
        float gg = tanhf(gate_s[eb][ejl * 4 + 2] + bs[2]);
        float oo = sigf (gate_s[eb][ejl * 4 + 3] + bs[3]);
        float cn = ff * c1r + ii * gg; c1r = cn;
        h_s[eb][ejl] = oo * tanhf(cn);
      }
      __syncthreads();
      if (tid < 32){
        unsigned short hb[4];
        #pragma unroll
        for (int jl = 0; jl < 4; ++jl) hb[jl] = f2b(h_s[tid][jl]);
        unsigned long long vb; __builtin_memcpy(&vb, hb, 8);
        astu((unsigned long long*)(P.Xh1 + p * 16384 + tid * 512 + bb * 4), vb);
        *(unsigned long long*)(P.mlpin + ((size_t)t * 32 + tid) * 1024 + bb * 4) = vb;
        unsigned long long w0, w1;
        __builtin_memcpy(&w0, &h_s[tid][0], 8);
        __builtin_memcpy(&w1, &h_s[tid][2], 8);
        unsigned long long* dst = (unsigned long long*)P.Xh1f + ((p * 16384 + tid * 512 + bb * 4) >> 1);
        astu(dst, w0); astu(dst + 1, w1);
      }
    }
    gbar(P.bar, phb + 3u);
    // ================= S34: attention (scores+softmax+context) =================
    {
      unsigned long long v = aldu((const unsigned long long*)(P.Xh1f + p * 16384 + b_att * 512) + tid);
      float f2[2]; __builtin_memcpy(f2, &v, 8);
      h1_s[tid * 2] = f2[0]; h1_s[tid * 2 + 1] = f2[1];
    }
    __syncthreads();
    {
      const int ti_l = tid >> 1, half = tid & 1;
      float s = 0.f;
      const unsigned swz = (unsigned)(ti_l & 7) << 4;
      for (int h8 = half * 256; h8 < half * 256 + 256; h8 += 8){
        unsigned byteoff = ((unsigned)(ti_l * 512 + h8) * 2u) ^ swz;
        s16x8 ev = *(const s16x8*)((const char*)enc_s + byteoff);
        #pragma unroll
        for (int e = 0; e < 8; ++e) s += b2f((unsigned short)ev[e]) * h1_s[h8 + e];
      }
      s += __shfl_xor(s, 1);
      if (half == 0) w_s[ti_l] = expf(s);       // no max-shift: |s| << 88
    }
    __syncthreads();
    {
      if (tid < 128){
        float z = w_s[tid];
        #pragma unroll
        for (int off = 1; off < 64; off <<= 1) z += __shfl_xor(z, off);
        if ((tid & 63) == 0) unsafeAtomicAdd(P.Zb + p * 32 + b_att, z);
      }
      // context: each thread owns h-pair (2 bf16 = one b32 LDS read per ti)
      float a0 = 0.f, a1 = 0.f;
      const int hc = tid * 2;
      for (int ti = 0; ti < 128; ++ti){
        const float wvv = w_s[ti];
        unsigned byteoff = ((unsigned)(ti * 1024 + hc * 2)) ^ ((unsigned)(ti & 7) << 4);
        unsigned pk = *(const unsigned*)((const char*)enc_s + byteoff);
        a0 += wvv * b2f((unsigned short)(pk & 0xffffu));
        a1 += wvv * b2f((unsigned short)(pk >> 16));
      }
      unsafeAtomicAdd(P.u + p * 16384 + b_att * 512 + hc, a0);
      unsafeAtomicAdd(P.u + p * 16384 + b_att * 512 + hc + 1, a1);
    }
    gbar(P.bar, phb + 4u);
  }
  // final att_c (t=256, p=0)
  if (bb >= 128 && bb < 160){
    const int b = bb - 128;
    const float rZ = 1.f / aldf(P.Zb + 0 * 32 + b);
    unsigned long long v = aldu((const unsigned long long*)(P.u + 0 * 16384 + b * 512) + tid);
    float f2[2]; __builtin_memcpy(f2, &v, 8);
    unsigned pk = (unsigned)f2b(f2[0] * rZ) | ((unsigned)f2b(f2[1] * rZ) << 16);
    *(unsigned*)(P.mlpin + ((size_t)256 * 32 + b) * 1024 + 512 + tid * 2) = pk;
  }
}

// ------------------------------------------------------------------
// B1: tanhv = tanh(mlpin @ W1^T + b1)   M=8224 N=512 K=1024, bf16 MFMA
__global__ __launch_bounds__(256) void kB1(Ptrs P){
  const int wid = blockIdx.x * 4 + (threadIdx.x >> 6);
  if (wid >= 129 * 8) return;
  const int mt = wid >> 3, nt = wid & 7;
  const int l = threadIdx.x & 63, lr = l & 15, lk = l >> 4;
  const int mr = mt * 64, nc = nt * 64;
  f32x4 acc[4][4] = {};
  for (int k0 = 0; k0 < 1024; k0 += 32){
    s16x8 af[4], bfm[4];
    #pragma unroll
    for (int f = 0; f < 4; ++f){
      int row = mr + f * 16 + lr; if (row > NROW_ - 1) row = NROW_ - 1;
      af[f] = *(const s16x8*)(P.mlpin + (size_t)row * 1024 + k0 + lk * 8);
      int col = nc + f * 16 + lr;
      bfm[f] = *(const s16x8*)(P.W1b + (size_t)col * 1024 + k0 + lk * 8);
    }
    #pragma unroll
    for (int fi = 0; fi < 4; ++fi)
      #pragma unroll
      for (int fj = 0; fj < 4; ++fj)
        acc[fi][fj] = __builtin_amdgcn_mfma_f32_16x16x32_bf16(af[fi], bfm[fj], acc[fi][fj], 0, 0, 0);
  }
  #pragma unroll
  for (int fi = 0; fi < 4; ++fi){
    #pragma unroll
    for (int jj = 0; jj < 4; ++jj){
      int m = mr + fi * 16 + lk * 4 + jj;
      if (m >= NROW_) continue;
      #pragma unroll
      for (int fj = 0; fj < 4; ++fj){
        int n = nc + fj * 16 + lr;
        P.tanhv[(size_t)m * 512 + n] = f2b(tanhf(acc[fi][fj][jj] + P.b1[n]));
      }
    }
  }
}

// B2: logits = tanhv @ W2^T + b2, fused exp-rowsum.  M=8224 N=10000 K=512
__global__ __launch_bounds__(256) void kB2(Ptrs P){
  const int wid = blockIdx.x * 4 + (threadIdx.x >> 6);
  if (wid >= 129 * 157) return;
  const int mt = wid / 157, nt = wid % 157;
  const int l = threadIdx.x & 63, lr = l & 15, lk = l >> 4;
  const int mr = mt * 64, nc = nt * 64;
  f32x4 acc[4][4] = {};
  for (int k0 = 0; k0 < 512; k0 += 32){
    s16x8 af[4], bfm[4];
    #pragma unroll
    for (int f = 0; f < 4; ++f){
      int row = mr + f * 16 + lr; if (row > NROW_ - 1) row = NROW_ - 1;
      af[f] = *(const s16x8*)(P.tanhv + (size_t)row * 512 + k0 + lk * 8);
      int col = nc + f * 16 + lr; if (col > V_ - 1) col = V_ - 1;
      bfm[f] = *(const s16x8*)(P.W2b + (size_t)col * 512 + k0 + lk * 8);
    }
    #pragma unroll
    for (int fi = 0; fi < 4; ++fi)
      #pragma unroll
      for (int fj = 0; fj < 4; ++fj)
        acc[fi][fj] = __builtin_amdgcn_mfma_f32_16x16x32_bf16(af[fi], bfm[fj], acc[fi][fj], 0, 0, 0);
  }
  #pragma unroll
  for (int fi = 0; fi < 4; ++fi){
    #pragma unroll
    for (int jj = 0; jj < 4; ++jj){
      const int m = mr + fi * 16 + lk * 4 + jj;
      float s = 0.f;
      #pragma unroll
      for (int fj = 0; fj < 4; ++fj){
        int n = nc + fj * 16 + lr;
        if (n < V_) s += expf(acc[fi][fj][jj] + P.b2[n]);
      }
      s += __shfl_xor(s, 1); s += __shfl_xor(s, 2);
      s += __shfl_xor(s, 4); s += __shfl_xor(s, 8);
      if (lr == 0 && m < NROW_) unsafeAtomicAdd(P.rowsum + m, s);
    }
  }
}

// label logit per row (one wave per row)
__global__ __launch_bounds__(256) void kL1(Ptrs P){
  const int wid = blockIdx.x * 4 + (threadIdx.x >> 6);
  if (wid >= NROW_) return;
  const int l = threadIdx.x & 63;
  const int t = wid >> 5, b = wid & 31;
  const int lab = (t < TO_) ? P.padded[b * TO_ + t] : 2;   // EOS=2
  float s = 0.f;
  s16x8 av = *(const s16x8*)(P.tanhv + (size_t)wid * 512 + l * 8);
  s16x8 wv = *(const s16x8*)(P.W2b + (size_t)lab * 512 + l * 8);
  #pragma unroll
  for (int e = 0; e < 8; ++e) s += b2f((unsigned short)av[e]) * b2f((unsigned short)wv[e]);
  #pragma unroll
  for (int off = 1; off < 64; off <<= 1) s += __shfl_xor(s, off);
  if (l == 0) P.lablog[wid] = s + P.b2[lab];
}

// final masked-NLL reduction
__global__ __launch_bounds__(512) void kL2(Ptrs P){
  __shared__ float ssum[8], scnt[8];
  const int tid = threadIdx.x;
  float sum = 0.f, cnt = 0.f;
  for (int r = tid; r < NROW_; r += 512){
    int t = r >> 5, b = r & 31;
    int lab = (t < TO_) ? P.padded[b * TO_ + t] : 2;
    if (lab != 0){ sum += logf(P.rowsum[r]) - P.lablog[r]; cnt += 1.f; }
  }
  #pragma unroll
  for (int off = 1; off < 64; off <<= 1){ sum += __shfl_xor(sum, off); cnt += __shfl_xor(cnt, off); }
  if ((tid & 63) == 0){ ssum[tid >> 6] = sum; scnt[tid >> 6] = cnt; }
  __syncthreads();
  if (tid == 0){
    float S = 0.f, C = 0.f;
    for (int i = 0; i < 8; ++i){ S += ssum[i]; C += scnt[i]; }
    P.out[0] = S / fmaxf(C, 1.f);
  }
}

// ------------------------------------------------------------------
extern "C" void kernel_launch(void* const* d_in, const int* in_sizes, int n_in,
                              void* d_out, int out_size, void* d_ws, size_t ws_size,
                              hipStream_t stream){
  (void)in_sizes; (void)n_in; (void)out_size; (void)ws_size;
  Ptrs P;
  P.padded = (const int*)d_in[0];
  P.enc    = (const float*)d_in[1];
  P.emb    = (const float*)d_in[2];
  P.Wih0 = (const float*)d_in[3];  P.Whh0 = (const float*)d_in[4];
  P.bih0 = (const float*)d_in[5];  P.bhh0 = (const float*)d_in[6];
  P.Wih1 = (const float*)d_in[7];  P.Whh1 = (const float*)d_in[8];
  P.bih1 = (const float*)d_in[9];  P.bhh1 = (const float*)d_in[10];
  P.W1 = (const float*)d_in[11];   P.b1 = (const float*)d_in[12];
  P.W2 = (const float*)d_in[13];   P.b2 = (const float*)d_in[14];
  P.out = (float*)d_out;

  char* w = (char*)d_ws;
  size_t off = 0;
  auto take = [&](size_t bytes) -> void* {
    void* ptr = (void*)(w + off);
    off += (bytes + 255) & ~(size_t)255;
    return ptr;
  };
  P.mlpin  = (unsigned short*)take((size_t)T_ * B_ * 1024 * 2);   // 16.84 MB
  P.embt   = (unsigned short*)take((size_t)T_ * B_ * 512 * 2);    // 8.42 MB
  P.tanhv  = P.embt;                                              // overlay (post-kA)
  P.W0c    = (unsigned short*)take((size_t)2048 * 1536 * 2);      // 6.29 MB
  P.W1c    = (unsigned short*)take((size_t)2048 * 1024 * 2);      // 4.19 MB
  P.W2b    = P.W0c;                                               // overlay (post-kA)
  P.W1b    = (unsigned short*)take((size_t)512 * 1024 * 2);       // 1.05 MB
  P.bias0c = (float*)take(2048 * 4);
  P.bias1c = (float*)take(2048 * 4);
  P.u      = (float*)take(2 * 32 * 512 * 4);
  P.Xh0    = (unsigned short*)take(2 * 32 * 512 * 2);
  P.Xh1    = (unsigned short*)take(2 * 32 * 512 * 2);
  P.Xh1f   = (float*)take(2 * 32 * 512 * 4);
  P.Zb     = (float*)take(2 * 32 * 4);
  P.bar    = (unsigned*)take(8192);
  P.rowsum = (float*)take(NROW_ * 4);
  P.lablog = (float*)take(NROW_ * 4);

  kprep<<<dim3(2048), dim3(256), 0, stream>>>(P);
  void* args[] = { (void*)&P };
  hipLaunchCooperativeKernel(kA, dim3(NB_), dim3(256), args, 0, stream);
  kprep2<<<dim3(1024), dim3(256), 0, stream>>>(P);
  kB1<<<dim3(258),  dim3(256), 0, stream>>>(P);
  kB2<<<dim3(5064), dim3(256), 0, stream>>>(P);
  kL1<<<dim3(2056), dim3(256), 0, stream>>>(P);
  kL2<<<dim3(1),    dim3(512), 0, stream>>>(P);
}

// Round 5
// 7713.962 us; speedup vs baseline: 7.6392x; 1.2252x over previous
//
#include <hip/hip_runtime.h>
#include <hip/hip_bf16.h>

// Problem constants
#define B_    32
#define TO_   256
#define T_    257        // To+1 decode steps
#define H_    512
#define V_    10000
#define TI_   1024
#define NROW_ 8224       // T_*B_
#define NB_   256        // blocks in cooperative kernel

using f32x4 = __attribute__((ext_vector_type(4))) float;
using s16x8 = __attribute__((ext_vector_type(8))) short;
typedef unsigned long long ull;

struct Ptrs {
  const int* padded;
  const float* enc;
  const float* emb;
  const float *Wih0, *Whh0, *bih0, *bhh0;
  const float *Wih1, *Whh1, *bih1, *bhh1;
  const float *W1, *b1, *W2, *b2;
  float* out;
  // workspace
  unsigned short *mlpin;   // [257][32][1024] bf16  (=[h1 | att_c])
  unsigned short *embt;    // [257][32][512] bf16 embedded tokens; tanhv overlays after kA
  unsigned short *tanhv;   // [8224][512] bf16 (== embt region)
  unsigned short *W0c;     // [2048][1536] bf16, row g'=j*4+q = [Wih0row | Whh0row]; W2b overlays
  unsigned short *W1c;     // [2048][1024] bf16, row g'=j*4+q = [Wih1row | Whh1row]
  unsigned short *W1b;     // [512][1024] bf16
  unsigned short *W2b;     // [10000][512] bf16 (== W0c region, filled by kprep2)
  float *bias0c, *bias1c;  // [2048] combined biases, gate-interleaved
  unsigned short *attc;    // [32][512] bf16 pre-normalized attention context
  float *upart;            // [32][8][512] f32 context partials (plain agent stores)
  float *zp;               // [32][8] softmax-denominator partials
  unsigned short *Xh0;     // [2][32][512] bf16 h0 state
  unsigned short *Xh1;     // [2][32][512] bf16 h1 state
  float *Xh1f;             // [2][32][512] f32 h1 state (attention)
  unsigned *arrX;          // [128*4] GEMM-only barrier flags
  unsigned *arrY;          // [128*4] h1-ready flags (GEMM arrive, all wait)
  unsigned *marr;          // [256*4] per-block partial-done flags
  unsigned *larr;          // [32*4]  per-batch context-ready flags
  unsigned *ibar;          // [256*4] init barrier flags
  float *rowsum;           // [8224]
  float *lablog;           // [8224]
};

__device__ __forceinline__ unsigned short f2b(float f){
  __hip_bfloat16 h = __float2bfloat16(f);
  unsigned short r; __builtin_memcpy(&r, &h, 2); return r;
}
__device__ __forceinline__ float b2f(unsigned short u){
  unsigned v = ((unsigned)u) << 16; float f; __builtin_memcpy(&f, &v, 4); return f;
}
__device__ __forceinline__ float sigf(float x){ return 1.f / (1.f + expf(-x)); }

// ---- agent-scope (device) relaxed atomics: bypass non-coherent L1/L2 ----
__device__ __forceinline__ float aldf(const float* p){
  return __hip_atomic_load(p, __ATOMIC_RELAXED, __HIP_MEMORY_SCOPE_AGENT);
}
__device__ __forceinline__ unsigned aldw(const unsigned* p){
  return __hip_atomic_load(p, __ATOMIC_RELAXED, __HIP_MEMORY_SCOPE_AGENT);
}
__device__ __forceinline__ ull aldu(const ull* p){
  return __hip_atomic_load(p, __ATOMIC_RELAXED, __HIP_MEMORY_SCOPE_AGENT);
}
__device__ __forceinline__ void astf(float* p, float v){
  __hip_atomic_store(p, v, __ATOMIC_RELAXED, __HIP_MEMORY_SCOPE_AGENT);
}
__device__ __forceinline__ void astu(ull* p, ull v){
  __hip_atomic_store(p, v, __ATOMIC_RELAXED, __HIP_MEMORY_SCOPE_AGENT);
}
__device__ __forceinline__ void astw(unsigned* p, unsigned v){
  __hip_atomic_store(p, v, __ATOMIC_RELAXED, __HIP_MEMORY_SCOPE_AGENT);
}
#define DRAIN asm volatile("s_waitcnt vmcnt(0)" ::: "memory")

// full-grid init barrier (flag array, ph=1)
__device__ __forceinline__ void gbarInit(unsigned* bar){
  DRAIN; __syncthreads();
  if (threadIdx.x < 64){
    const int l = threadIdx.x;
    if (l == 0) astw(bar + blockIdx.x * 4, 1u);
    for (;;){
      unsigned f0 = aldw(bar + (l      ) * 4);
      unsigned f1 = aldw(bar + (l +  64) * 4);
      unsigned f2 = aldw(bar + (l + 128) * 4);
      unsigned f3 = aldw(bar + (l + 192) * 4);
      if (__all((f0 >= 1u) & (f1 >= 1u) & (f2 >= 1u) & (f3 >= 1u))) break;
      __builtin_amdgcn_s_sleep(1);
    }
  }
  __syncthreads();
}

// ------------------------------------------------------------------
__global__ __launch_bounds__(256) void kprep(Ptrs P){
  const int stride = gridDim.x * blockDim.x;
  const int i0 = blockIdx.x * blockDim.x + threadIdx.x;
  for (int i = i0; i < 128 * 4; i += stride){ P.arrX[i] = 0u; P.arrY[i] = 0u; }
  for (int i = i0; i < 256 * 4; i += stride){ P.marr[i] = 0u; P.ibar[i] = 0u; }
  for (int i = i0; i < 32 * 4; i += stride) P.larr[i] = 0u;
  for (int i = i0; i < T_ * B_ * 512; i += stride){
    int k = i & 511, tb = i >> 9, b = tb & 31, t = tb >> 5;
    int tok = (t == 0) ? 1 : P.padded[b * TO_ + (t - 1)];
    P.embt[i] = f2b(P.emb[(size_t)tok * 512 + k]);
  }
  for (int i = i0; i < 2048 * 1536; i += stride){
    int k = i % 1536, gp = i / 1536;
    int j = gp >> 2, q = gp & 3, g = q * 512 + j;
    float v = (k < 1024) ? P.Wih0[(size_t)g * 1024 + k] : P.Whh0[(size_t)g * 512 + (k - 1024)];
    P.W0c[i] = f2b(v);
  }
  for (int i = i0; i < 2048 * 1024; i += stride){
    int k = i & 1023, gp = i >> 10;
    int j = gp >> 2, q = gp & 3, g = q * 512 + j;
    float v = (k < 512) ? P.Wih1[(size_t)g * 512 + k] : P.Whh1[(size_t)g * 512 + (k - 512)];
    P.W1c[i] = f2b(v);
  }
  for (int i = i0; i < 2048; i += stride){
    int j = i >> 2, q = i & 3, g = q * 512 + j;
    P.bias0c[i] = P.bih0[g] + P.bhh0[g];
    P.bias1c[i] = P.bih1[g] + P.bhh1[g];
  }
  for (int i = i0; i < 512 * 1024; i += stride) P.W1b[i] = f2b(P.W1[i]);
  for (int i = i0; i < NROW_; i += stride) P.rowsum[i] = 0.f;
}

__global__ __launch_bounds__(256) void kprep2(Ptrs P){
  const int stride = gridDim.x * blockDim.x;
  const int i0 = blockIdx.x * blockDim.x + threadIdx.x;
  for (int i = i0; i < V_ * 512; i += stride) P.W2b[i] = f2b(P.W2[i]);
}

// ------------------------------------------------------------------
// Phase A. Per step t:
//  GEMM blocks (0-127): poll larr>=t ; S1 GEMM -> Xh0 ; arrX ; S2 GEMM -> h1 ;
//                       arrive arrY ; [join S34]
//  All blocks: wait arrY>=t+1 ; S34 scores+partials ; marr flag.
//  Reducers (128-159, rb=bb-128): poll marr[rb][0..7] ; reduce 8 partials+Z ;
//                       publish attc bf16 + mlpin att_c ; larr flag.
__global__ __launch_bounds__(256, 1) void kA(Ptrs P){
  __shared__ __align__(16) unsigned short enc_s[128 * 512]; // 128 KB, XOR-swizzled
  __shared__ float h1_s[512];
  __shared__ float w_s[128];
  __shared__ float gate_s[2][32][17];
  __shared__ float h_s[32][4];
  __shared__ float zred[2];
  const int bb = blockIdx.x, tid = threadIdx.x;
  const int b_att = bb >> 3, tc = bb & 7;

  { // stage encoder slice -> LDS bf16 with byte^=((row&7)<<4) swizzle
    const float* ep = P.enc + ((size_t)b_att * TI_ + (size_t)tc * 128) * H_;
    for (int idx = tid; idx < 128 * 512; idx += 256){
      int r = idx >> 9;
      unsigned byteoff = ((unsigned)idx * 2u) ^ ((unsigned)(r & 7) << 4);
      enc_s[byteoff >> 1] = f2b(ep[idx]);
    }
  }
  { // zero recurrent state + attc
    int g = bb * 256 + tid;
    if (g < 16384){ astw((unsigned*)P.Xh0 + g, 0u); astw((unsigned*)P.Xh1 + g, 0u); }
    if (g < 32768) astf(P.Xh1f + g, 0.f);
    if (g < 8192)  astw((unsigned*)P.attc + g, 0u);
  }
  gbarInit(P.ibar);

  const int wv = tid >> 6, l = tid & 63, lr = l & 15, lk = l >> 4;
  const int bh = wv & 1, kh = wv >> 1;          // batch-half, K-half
  const int batch = bh * 16 + lr;
  const int eidx = tid - 128, eb = eidx >> 2, ejl = eidx & 3;
  const bool isGemm = bb < 128;
  const int rb = bb - 128; const bool isRed = (rb >= 0 && rb < 32);
  float c0r = 0.f, c1r = 0.f;

  for (int t = 0; t < T_; ++t){
    const int p = t & 1, pp = p ^ 1;
    const unsigned tv = (unsigned)t + 1u;
    if (isGemm){
      // ---- wait: att context (t-1) published ----
      if (t > 0 && tid < 64){
        const unsigned want = tv - 1u;
        for (;;){
          unsigned f = (tid < 32) ? aldw(P.larr + tid * 4) : want;
          if (__all(f >= want)) break;
          __builtin_amdgcn_s_sleep(1);
        }
      }
      __syncthreads();
      // ---- S1: layer-0 GEMM (K split across wave pairs) ----
      {
        const unsigned short* Brow = P.W0c + (size_t)(bb * 16 + lr) * 1536;
        const unsigned short* Erow = P.embt + ((size_t)t * 32 + batch) * 512;
        const ull* Arow = (const ull*)(P.attc + batch * 512);
        const ull* Hrow = (const ull*)(P.Xh0 + pp * 16384 + batch * 512);
        f32x4 acc = {0.f, 0.f, 0.f, 0.f};
        #pragma unroll
        for (int ks = 0; ks < 8; ++ks){
          const int kb = (kh * 8 + ks) * 32 + lk * 8;
          s16x8 a = *(const s16x8*)(Erow + kb);
          s16x8 b = *(const s16x8*)(Brow + kb);
          acc = __builtin_amdgcn_mfma_f32_16x16x32_bf16(a, b, acc, 0, 0, 0);
        }
        #pragma unroll
        for (int ks = 0; ks < 8; ++ks){
          const int kb = (kh * 8 + ks) * 32 + lk * 8;
          ull d0 = aldu(Arow + (kb >> 2)), d1 = aldu(Arow + (kb >> 2) + 1);
          s16x8 a; __builtin_memcpy(&a, &d0, 8); __builtin_memcpy(((char*)&a) + 8, &d1, 8);
          s16x8 b = *(const s16x8*)(Brow + 512 + kb);
          acc = __builtin_amdgcn_mfma_f32_16x16x32_bf16(a, b, acc, 0, 0, 0);
        }
        #pragma unroll
        for (int ks = 0; ks < 8; ++ks){
          const int kb = (kh * 8 + ks) * 32 + lk * 8;
          ull d0 = aldu(Hrow + (kb >> 2)), d1 = aldu(Hrow + (kb >> 2) + 1);
          s16x8 a; __builtin_memcpy(&a, &d0, 8); __builtin_memcpy(((char*)&a) + 8, &d1, 8);
          s16x8 b = *(const s16x8*)(Brow + 1024 + kb);
          acc = __builtin_amdgcn_mfma_f32_16x16x32_bf16(a, b, acc, 0, 0, 0);
        }
        #pragma unroll
        for (int j = 0; j < 4; ++j) gate_s[kh][bh * 16 + lk * 4 + j][lr] = acc[j];
      }
      __syncthreads();
      if (tid >= 128){
        const float* bs = P.bias0c + bb * 16 + ejl * 4;
        float ii = sigf (gate_s[0][eb][ejl * 4 + 0] + gate_s[1][eb][ejl * 4 + 0] + bs[0]);
        float ff = sigf (gate_s[0][eb][ejl * 4 + 1] + gate_s[1][eb][ejl * 4 + 1] + bs[1]);
        float gg = tanhf(gate_s[0][eb][ejl * 4 + 2] + gate_s[1][eb][ejl * 4 + 2] + bs[2]);
        float oo = sigf (gate_s[0][eb][ejl * 4 + 3] + gate_s[1][eb][ejl * 4 + 3] + bs[3]);
        float cn = ff * c0r + ii * gg; c0r = cn;
        h_s[eb][ejl] = oo * tanhf(cn);
      }
      __syncthreads();
      if (tid < 32){
        unsigned short hb[4];
        #pragma unroll
        for (int jl = 0; jl < 4; ++jl) hb[jl] = f2b(h_s[tid][jl]);
        ull v; __builtin_memcpy(&v, hb, 8);
        astu((ull*)(P.Xh0 + p * 16384 + tid * 512 + bb * 4), v);
      }
      // ---- arrX: 128-block rendezvous ----
      DRAIN; __syncthreads();
      if (tid < 64){
        if (tid == 0) astw(P.arrX + bb * 4, tv);
        for (;;){
          unsigned f0 = aldw(P.arrX + tid * 4), f1 = aldw(P.arrX + (tid + 64) * 4);
          if (__all((f0 >= tv) & (f1 >= tv))) break;
          __builtin_amdgcn_s_sleep(1);
        }
      }
      __syncthreads();
      // ---- S2: layer-1 GEMM ----
      {
        const unsigned short* Brow = P.W1c + (size_t)(bb * 16 + lr) * 1024;
        const ull* H0r = (const ull*)(P.Xh0 + p * 16384 + batch * 512);
        const ull* H1r = (const ull*)(P.Xh1 + pp * 16384 + batch * 512);
        f32x4 acc = {0.f, 0.f, 0.f, 0.f};
        #pragma unroll
        for (int ks = 0; ks < 8; ++ks){
          const int kb = (kh * 8 + ks) * 32 + lk * 8;
          ull d0 = aldu(H0r + (kb >> 2)), d1 = aldu(H0r + (kb >> 2) + 1);
          s16x8 a; __builtin_memcpy(&a, &d0, 8); __builtin_memcpy(((char*)&a) + 8, &d1, 8);
          s16x8 b = *(const s16x8*)(Brow + kb);
          acc = __builtin_amdgcn_mfma_f32_16x16x32_bf16(a, b, acc, 0, 0, 0);
        }
        #pragma unroll
        for (int ks = 0; ks < 8; ++ks){
          const int kb = (kh * 8 + ks) * 32 + lk * 8;
          ull d0 = aldu(H1r + (kb >> 2)), d1 = aldu(H1r + (kb >> 2) + 1);
          s16x8 a; __builtin_memcpy(&a, &d0, 8); __builtin_memcpy(((char*)&a) + 8, &d1, 8);
          s16x8 b = *(const s16x8*)(Brow + 512 + kb);
          acc = __builtin_amdgcn_mfma_f32_16x16x32_bf16(a, b, acc, 0, 0, 0);
        }
        #pragma unroll
        for (int j = 0; j < 4; ++j) gate_s[kh][bh * 16 + lk * 4 + j][lr] = acc[j];
      }
      __syncthreads();
      if (tid >= 128){
        const float* bs = P.bias1c + bb * 16 + ejl * 4;
        float ii = sigf (gate_s[0][eb][ejl * 4 + 0] + gate_s[1][eb][ejl * 4 + 0] + bs[0]);
        float ff = sigf (gate_s[0][eb][ejl * 4 + 1] + gate_s[1][eb][ejl * 4 + 1] + bs[1]);
        float gg = tanhf(gate_s[0][eb][ejl * 4 + 2] + gate_s[1][eb][ejl * 4 + 2] + bs[2]);
        float oo = sigf (gate_s[0][eb][ejl * 4 + 3] + gate_s[1][eb][ejl * 4 + 3] + bs[3]);
        float cn = ff * c1r + ii * gg; c1r = cn;
        h_s[eb][ejl] = oo * tanhf(cn);
      }
      __syncthreads();
      if (tid < 32){
        unsigned short hb[4];
        #pragma unroll
        for (int jl = 0; jl < 4; ++jl) hb[jl] = f2b(h_s[tid][jl]);
        ull vb; __builtin_memcpy(&vb, hb, 8);
        astu((ull*)(P.Xh1 + p * 16384 + tid * 512 + bb * 4), vb);
        *(ull*)(P.mlpin + ((size_t)t * 32 + tid) * 1024 + bb * 4) = vb;
        ull w0, w1;
        __builtin_memcpy(&w0, &h_s[tid][0], 8);
        __builtin_memcpy(&w1, &h_s[tid][2], 8);
        ull* dst = (ull*)P.Xh1f + ((p * 16384 + tid * 512 + bb * 4) >> 1);
        astu(dst, w0); astu(dst + 1, w1);
      }
      DRAIN; __syncthreads();
      if (tid == 0) astw(P.arrY + bb * 4, tv);
    }
    // ---- arrY wait: h1(t) ready (all blocks) ----
    if (tid < 64){
      for (;;){
        unsigned f0 = aldw(P.arrY + tid * 4), f1 = aldw(P.arrY + (tid + 64) * 4);
        if (__all((f0 >= tv) & (f1 >= tv))) break;
        __builtin_amdgcn_s_sleep(1);
      }
    }
    __syncthreads();
    // ---- S34: scores + softmax partials + context partials ----
    {
      ull v = aldu((const ull*)(P.Xh1f + p * 16384 + b_att * 512) + tid);
      float f2[2]; __builtin_memcpy(f2, &v, 8);
      h1_s[tid * 2] = f2[0]; h1_s[tid * 2 + 1] = f2[1];
    }
    __syncthreads();
    {
      const int ti_l = tid >> 1, half = tid & 1;
      float s = 0.f;
      const unsigned swz = (unsigned)(ti_l & 7) << 4;
      for (int h8 = half * 256; h8 < half * 256 + 256; h8 += 8){
        unsigned byteoff = ((unsigned)(ti_l * 512 + h8) * 2u) ^ swz;
        s16x8 ev = *(const s16x8*)((const char*)enc_s + byteoff);
        #pragma unroll
        for (int e = 0; e < 8; ++e) s += b2f((unsigned short)ev[e]) * h1_s[h8 + e];
      }
      s += __shfl_xor(s, 1);
      if (half == 0) w_s[ti_l] = expf(s);       // no max-shift: |s| << 88
    }
    __syncthreads();
    {
      if (tid < 128){
        float z = w_s[tid];
        #pragma unroll
        for (int off = 1; off < 64; off <<= 1) z += __shfl_xor(z, off);
        if ((tid & 63) == 0) zred[tid >> 6] = z;
      }
      float a0 = 0.f, a1 = 0.f;
      const int hc = tid * 2;
      for (int ti = 0; ti < 128; ++ti){
        const float wvv = w_s[ti];
        unsigned byteoff = ((unsigned)(ti * 1024 + hc * 2)) ^ ((unsigned)(ti & 7) << 4);
        unsigned pk = *(const unsigned*)((const char*)enc_s + byteoff);
        a0 += wvv * b2f((unsigned short)(pk & 0xffffu));
        a1 += wvv * b2f((unsigned short)(pk >> 16));
      }
      float f2[2] = {a0, a1};
      ull pv; __builtin_memcpy(&pv, f2, 8);
      astu((ull*)(P.upart + ((size_t)b_att * 8 + tc) * 512 + hc), pv);
      __syncthreads();
      if (tid == 0) astf(P.zp + b_att * 8 + tc, zred[0] + zred[1]);
      DRAIN; __syncthreads();
      if (tid == 0) astw(P.marr + (b_att * 8 + tc) * 4, tv);
    }
    // ---- reducer tail: publish attc(t) ----
    if (isRed){
      if (tid < 64){
        for (;;){
          unsigned f = (tid < 8) ? aldw(P.marr + (rb * 8 + tid) * 4) : tv;
          if (__all(f >= tv)) break;
          __builtin_amdgcn_s_sleep(1);
        }
      }
      __syncthreads();
      const int hc = tid * 2;
      float s0 = 0.f, s1 = 0.f, zs = 0.f;
      #pragma unroll
      for (int c = 0; c < 8; ++c){
        ull v = aldu((const ull*)(P.upart + ((size_t)rb * 8 + c) * 512 + hc));
        float f2[2]; __builtin_memcpy(f2, &v, 8);
        s0 += f2[0]; s1 += f2[1];
        zs += aldf(P.zp + rb * 8 + c);
      }
      const float rZ = 1.f / zs;
      unsigned pk = (unsigned)f2b(s0 * rZ) | ((unsigned)f2b(s1 * rZ) << 16);
      astw(((unsigned*)P.attc) + rb * 256 + tid, pk);
      *(unsigned*)(P.mlpin + ((size_t)t * 32 + rb) * 1024 + 512 + hc) = pk;
      DRAIN; __syncthreads();
      if (tid == 0) astw(P.larr + rb * 4, tv);
    }
  }
}

// ------------------------------------------------------------------
// B1: tanhv = tanh(mlpin @ W1^T + b1)   M=8224 N=512 K=1024, bf16 MFMA
__global__ __launch_bounds__(256) void kB1(Ptrs P){
  const int wid = blockIdx.x * 4 + (threadIdx.x >> 6);
  if (wid >= 129 * 8) return;
  const int mt = wid >> 3, nt = wid & 7;
  const int l = threadIdx.x & 63, lr = l & 15, lk = l >> 4;
  const int mr = mt * 64, nc = nt * 64;
  f32x4 acc[4][4] = {};
  for (int k0 = 0; k0 < 1024; k0 += 32){
    s16x8 af[4], bfm[4];
    #pragma unroll
    for (int f = 0; f < 4; ++f){
      int row = mr + f * 16 + lr; if (row > NROW_ - 1) row = NROW_ - 1;
      af[f] = *(const s16x8*)(P.mlpin + (size_t)row * 1024 + k0 + lk * 8);
      int col = nc + f * 16 + lr;
      bfm[f] = *(const s16x8*)(P.W1b + (size_t)col * 1024 + k0 + lk * 8);
    }
    #pragma unroll
    for (int fi = 0; fi < 4; ++fi)
      #pragma unroll
      for (int fj = 0; fj < 4; ++fj)
        acc[fi][fj] = __builtin_amdgcn_mfma_f32_16x16x32_bf16(af[fi], bfm[fj], acc[fi][fj], 0, 0, 0);
  }
  #pragma unroll
  for (int fi = 0; fi < 4; ++fi){
    #pragma unroll
    for (int jj = 0; jj < 4; ++jj){
      int m = mr + fi * 16 + lk * 4 + jj;
      if (m >= NROW_) continue;
      #pragma unroll
      for (int fj = 0; fj < 4; ++fj){
        int n = nc + fj * 16 + lr;
        P.tanhv[(size_t)m * 512 + n] = f2b(tanhf(acc[fi][fj][jj] + P.b1[n]));
      }
    }
  }
}

// B2: logits = tanhv @ W2^T + b2, fused exp-rowsum.  M=8224 N=10000 K=512
__global__ __launch_bounds__(256) void kB2(Ptrs P){
  const int wid = blockIdx.x * 4 + (threadIdx.x >> 6);
  if (wid >= 129 * 157) return;
  const int mt = wid / 157, nt = wid % 157;
  const int l = threadIdx.x & 63, lr = l & 15, lk = l >> 4;
  const int mr = mt * 64, nc = nt * 64;
  f32x4 acc[4][4] = {};
  for (int k0 = 0; k0 < 512; k0 += 32){
    s16x8 af[4], bfm[4];
    #pragma unroll
    for (int f = 0; f < 4; ++f){
      int row = mr + f * 16 + lr; if (row > NROW_ - 1) row = NROW_ - 1;
      af[f] = *(const s16x8*)(P.tanhv + (size_t)row * 512 + k0 + lk * 8);
      int col = nc + f * 16 + lr; if (col > V_ - 1) col = V_ - 1;
      bfm[f] = *(const s16x8*)(P.W2b + (size_t)col * 512 + k0 + lk * 8);
    }
    #pragma unroll
    for (int fi = 0; fi < 4; ++fi)
      #pragma unroll
      for (int fj = 0; fj < 4; ++fj)
        acc[fi][fj] = __builtin_amdgcn_mfma_f32_16x16x32_bf16(af[fi], bfm[fj], acc[fi][fj], 0, 0, 0);
  }
  #pragma unroll
  for (int fi = 0; fi < 4; ++fi){
    #pragma unroll
    for (int jj = 0; jj < 4; ++jj){
      const int m = mr + fi * 16 + lk * 4 + jj;
      float s = 0.f;
      #pragma unroll
      for (int fj = 0; fj < 4; ++fj){
        int n = nc + fj * 16 + lr;
        if (n < V_) s += expf(acc[fi][fj][jj] + P.b2[n]);
      }
      s += __shfl_xor(s, 1); s += __shfl_xor(s, 2);
      s += __shfl_xor(s, 4); s += __shfl_xor(s, 8);
      if (lr == 0 && m < NROW_) unsafeAtomicAdd(P.rowsum + m, s);
    }
  }
}

// label logit per row (one wave per row)
__global__ __launch_bounds__(256) void kL1(Ptrs P){
  const int wid = blockIdx.x * 4 + (threadIdx.x >> 6);
  if (wid >= NROW_) return;
  const int l = threadIdx.x & 63;
  const int t = wid >> 5, b = wid & 31;
  const int lab = (t < TO_) ? P.padded[b * TO_ + t] : 2;   // EOS=2
  float s = 0.f;
  s16x8 av = *(const s16x8*)(P.tanhv + (size_t)wid * 512 + l * 8);
  s16x8 wv = *(const s16x8*)(P.W2b + (size_t)lab * 512 + l * 8);
  #pragma unroll
  for (int e = 0; e < 8; ++e) s += b2f((unsigned short)av[e]) * b2f((unsigned short)wv[e]);
  #pragma unroll
  for (int off = 1; off < 64; off <<= 1) s += __shfl_xor(s, off);
  if (l == 0) P.lablog[wid] = s + P.b2[lab];
}

// final masked-NLL reduction
__global__ __launch_bounds__(512) void kL2(Ptrs P){
  __shared__ float ssum[8], scnt[8];
  const int tid = threadIdx.x;
  float sum = 0.f, cnt = 0.f;
  for (int r = tid; r < NROW_; r += 512){
    int t = r >> 5, b = r & 31;
    int lab = (t < TO_) ? P.padded[b * TO_ + t] : 2;
    if (lab != 0){ sum += logf(P.rowsum[r]) - P.lablog[r]; cnt += 1.f; }
  }
  #pragma unroll
  for (int off = 1; off < 64; off <<= 1){ sum += __shfl_xor(sum, off); cnt += __shfl_xor(cnt, off); }
  if ((tid & 63) == 0){ ssum[tid >> 6] = sum; scnt[tid >> 6] = cnt; }
  __syncthreads();
  if (tid == 0){
    float S = 0.f, C = 0.f;
    for (int i = 0; i < 8; ++i){ S += ssum[i]; C += scnt[i]; }
    P.out[0] = S / fmaxf(C, 1.f);
  }
}

// ------------------------------------------------------------------
extern "C" void kernel_launch(void* const* d_in, const int* in_sizes, int n_in,
                              void* d_out, int out_size, void* d_ws, size_t ws_size,
                              hipStream_t stream){
  (void)in_sizes; (void)n_in; (void)out_size; (void)ws_size;
  Ptrs P;
  P.padded = (const int*)d_in[0];
  P.enc    = (const float*)d_in[1];
  P.emb    = (const float*)d_in[2];
  P.Wih0 = (const float*)d_in[3];  P.Whh0 = (const float*)d_in[4];
  P.bih0 = (const float*)d_in[5];  P.bhh0 = (const float*)d_in[6];
  P.Wih1 = (const float*)d_in[7];  P.Whh1 = (const float*)d_in[8];
  P.bih1 = (const float*)d_in[9];  P.bhh1 = (const float*)d_in[10];
  P.W1 = (const float*)d_in[11];   P.b1 = (const float*)d_in[12];
  P.W2 = (const float*)d_in[13];   P.b2 = (const float*)d_in[14];
  P.out = (float*)d_out;

  char* w = (char*)d_ws;
  size_t off = 0;
  auto take = [&](size_t bytes) -> void* {
    void* ptr = (void*)(w + off);
    off += (bytes + 255) & ~(size_t)255;
    return ptr;
  };
  P.mlpin  = (unsigned short*)take((size_t)T_ * B_ * 1024 * 2);   // 16.84 MB
  P.embt   = (unsigned short*)take((size_t)T_ * B_ * 512 * 2);    // 8.42 MB
  P.tanhv  = P.embt;                                              // overlay (post-kA)
  P.W0c    = (unsigned short*)take((size_t)2048 * 1536 * 2);      // 6.29 MB
  P.W1c    = (unsigned short*)take((size_t)2048 * 1024 * 2);      // 4.19 MB
  P.W2b    = P.W0c;                                               // overlay (post-kA)
  P.W1b    = (unsigned short*)take((size_t)512 * 1024 * 2);       // 1.05 MB
  P.bias0c = (float*)take(2048 * 4);
  P.bias1c = (float*)take(2048 * 4);
  P.attc   = (unsigned short*)take(32 * 512 * 2);
  P.upart  = (float*)take((size_t)32 * 8 * 512 * 4);              // 512 KB
  P.zp     = (float*)take(32 * 8 * 4);
  P.Xh0    = (unsigned short*)take(2 * 32 * 512 * 2);
  P.Xh1    = (unsigned short*)take(2 * 32 * 512 * 2);
  P.Xh1f   = (float*)take(2 * 32 * 512 * 4);
  P.arrX   = (unsigned*)take(128 * 4 * 4);
  P.arrY   = (unsigned*)take(128 * 4 * 4);
  P.marr   = (unsigned*)take(256 * 4 * 4);
  P.larr   = (unsigned*)take(32 * 4 * 4);
  P.ibar   = (unsigned*)take(256 * 4 * 4);
  P.rowsum = (float*)take(NROW_ * 4);
  P.lablog = (float*)take(NROW_ * 4);

  kprep<<<dim3(2048), dim3(256), 0, stream>>>(P);
  void* args[] = { (void*)&P };
  hipLaunchCooperativeKernel(kA, dim3(NB_), dim3(256), args, 0, stream);
  kprep2<<<dim3(1024), dim3(256), 0, stream>>>(P);
  kB1<<<dim3(258),  dim3(256), 0, stream>>>(P);
  kB2<<<dim3(5064), dim3(256), 0, stream>>>(P);
  kL1<<<dim3(2056), dim3(256), 0, stream>>>(P);
  kL2<<<dim3(1),    dim3(512), 0, stream>>>(P);
}